// Round 9
// baseline (301.549 us; speedup 1.0000x reference)
//
#include <hip/hip_runtime.h>

// SGFormer encoder layer, MI355X gfx950.
// fp32 I/O per reference dtypes; bf16 MFMA internally.
// R2: CSR+gather scatter-mean. R3/4: static-max flash attn, V^T, K-split.
// R5: SPLITS=4, merged LQKV gemm. R7: f2b_up P. R8: glls+XOR-swizzle staging.
// R9: algebraic fusion mixed@Wo^T -> one K=1024 GEMM with Wcat=[0.5Wo|0.5WoWa]
//     (Wc via tiny 512^3 gemm; bprime=bo+0.5Wo@ba in cvt slot); gather+vtrans
//     fused; mixed buffer gone. Non-attn chain was 232us, unchanged by R8 ->
//     dispatch count / serial traffic is the lever now.

#define N_NODES 4096
#define C_DIM   512
#define H_HEADS 8
#define D_HEAD  64
#define E_EDGES 131072

typedef unsigned short u16;
typedef unsigned int   u32;
typedef u16   u16x8  __attribute__((ext_vector_type(8)));
typedef __bf16 bf16x8 __attribute__((ext_vector_type(8)));
typedef float  f32x4  __attribute__((ext_vector_type(4)));

__device__ __forceinline__ float b2f(u16 u) {
  unsigned int i = ((unsigned int)u) << 16;
  return __builtin_bit_cast(float, i);
}
__device__ __forceinline__ u16 f2b(float f) {
  unsigned int i = __builtin_bit_cast(unsigned int, f);
  i += 0x7fffu + ((i >> 16) & 1u);   // RNE
  return (u16)(i >> 16);
}
__device__ __forceinline__ u16 f2b_up(float f) {   // round-half-up (cheaper)
  unsigned int i = __builtin_bit_cast(unsigned int, f);
  return (u16)((i + 0x8000u) >> 16);
}
// async global->LDS, 16B per lane; LDS dest = wave-uniform base + lane*16
__device__ __forceinline__ void glds16(const u16* g, u16* l) {
  __builtin_amdgcn_global_load_lds(
      (const __attribute__((address_space(1))) void*)g,
      (__attribute__((address_space(3))) void*)l, 16, 0, 0);
}

// ---------------- fp32 -> bf16 convert + hist + bprime matvec ----------------
struct CvtArgs {
  const float* src[7];
  u16* dst[7];
  int n[7];
  const int* ei;
  int* deg;
  u16* wbAT;            // t==3: Wa^T (transposed store)
  u16* wcat0;           // t==4: 0.5*Wo -> Wcat[:,0:512] (stride 1024)
  const float* wo_f32;  // t==8 matvec inputs
  const float* ba_f32;
  const float* bo_f32;
  float* bprime;
};

__global__ __launch_bounds__(256) void cvt_multi(CvtArgs a) {
  const int t = blockIdx.y;
  if (t == 7) {                       // fused degree histogram
    if (blockIdx.x >= E_EDGES / 256) return;
    const int e = blockIdx.x * 256 + threadIdx.x;
    atomicAdd(&a.deg[a.ei[E_EDGES + e]], 1);
    return;
  }
  if (t == 8) {                       // bprime = bo + 0.5*Wo@ba (fp32)
    const int n = blockIdx.x * 256 + threadIdx.x;
    if (n >= 512) return;
    const float* wrow = a.wo_f32 + (size_t)n * 512;
    float s = 0.0f;
    for (int k = 0; k < 512; k += 4) {
      f32x4 w4 = *(const f32x4*)(wrow + k);
      f32x4 b4 = *(const f32x4*)(a.ba_f32 + k);
      s += w4[0] * b4[0] + w4[1] * b4[1] + w4[2] * b4[2] + w4[3] * b4[3];
    }
    a.bprime[n] = a.bo_f32[n] + 0.5f * s;
    return;
  }
  const int i = (blockIdx.x * 256 + threadIdx.x) * 8;
  if (i >= a.n[t]) return;
  const float* s = a.src[t] + i;
  f32x4 v0 = *(const f32x4*)s;
  f32x4 v1 = *(const f32x4*)(s + 4);
  u16x8 o;
  o[0]=f2b(v0[0]); o[1]=f2b(v0[1]); o[2]=f2b(v0[2]); o[3]=f2b(v0[3]);
  o[4]=f2b(v1[0]); o[5]=f2b(v1[1]); o[6]=f2b(v1[2]); o[7]=f2b(v1[3]);
  if (t == 3) {                       // Wa^T only (scattered b16 writes)
    const int r = i >> 9, c = i & 511;
#pragma unroll
    for (int j = 0; j < 8; ++j) a.wbAT[(size_t)(c + j) * 512 + r] = o[j];
    return;
  }
  *(u16x8*)(a.dst[t] + i) = o;
  if (t == 4) {                       // also 0.5*Wo into Wcat[:,0:512]
    const int r = i >> 9, c = i & 511;
    u16x8 oh;
    oh[0]=f2b(v0[0]*0.5f); oh[1]=f2b(v0[1]*0.5f); oh[2]=f2b(v0[2]*0.5f); oh[3]=f2b(v0[3]*0.5f);
    oh[4]=f2b(v1[0]*0.5f); oh[5]=f2b(v1[1]*0.5f); oh[6]=f2b(v1[2]*0.5f); oh[7]=f2b(v1[3]*0.5f);
    *(u16x8*)(a.wcat0 + (size_t)r * 1024 + c) = oh;
  }
}

// ---------------- 64x64 tile GEMM: out = A[M,K] * W[*,K]^T + bias ----------
// EPI 1: f32 out (+bias). EPI 5: 0.5*v -> bf16, no bias (weight pre-multiply).
// glls staging, XOR-swizzled LDS (slot = granule ^ (row&7)).
template<int EPI>
__global__ __launch_bounds__(256) void gemm_bt(
    const u16* __restrict__ A, const u16* __restrict__ W,
    const float* __restrict__ bias, void* __restrict__ outp,
    int M, int Nout, int K)
{
  const int tid  = threadIdx.x;
  const int lane = tid & 63, wave = tid >> 6;
  const int quad = lane >> 4, l16 = lane & 15;
  const int wm = wave >> 1, wn = wave & 1;   // 2x2 wave grid, 32x32 per wave
  const int bm = blockIdx.x, bnb = blockIdx.y;

  __shared__ __align__(16) u16 As[64][64];
  __shared__ __align__(16) u16 Ws[64][64];

  f32x4 acc[2][2] = {};

  const int lr = lane >> 3, gs = lane & 7;
  const int g8 = (gs ^ lr) * 8;                  // u16 offset within row
  const u16* a0 = A + (size_t)(bm  * 64 + wave * 16 +     lr) * K + g8;
  const u16* a1 = A + (size_t)(bm  * 64 + wave * 16 + 8 + lr) * K + g8;
  const u16* w0 = W + (size_t)(bnb * 64 + wave * 16 +     lr) * K + g8;
  const u16* w1 = W + (size_t)(bnb * 64 + wave * 16 + 8 + lr) * K + g8;

  for (int k0 = 0; k0 < K; k0 += 64) {
    __syncthreads();                  // prior iter's LDS reads complete
    glds16(a0 + k0, &As[wave * 16][0]);
    glds16(a1 + k0, &As[wave * 16 + 8][0]);
    glds16(w0 + k0, &Ws[wave * 16][0]);
    glds16(w1 + k0, &Ws[wave * 16 + 8][0]);
    __syncthreads();                  // drains vmcnt (glls) before reads
#pragma unroll
    for (int ks = 0; ks < 2; ++ks) {
      const int slot = ((ks * 4 + quad) ^ (l16 & 7)) * 8;
      bf16x8 af[2], bf[2];
      af[0] = *(const bf16x8*)&As[wm * 32 +      l16][slot];
      af[1] = *(const bf16x8*)&As[wm * 32 + 16 + l16][slot];
      bf[0] = *(const bf16x8*)&Ws[wn * 32 +      l16][slot];
      bf[1] = *(const bf16x8*)&Ws[wn * 32 + 16 + l16][slot];
#pragma unroll
      for (int i = 0; i < 2; ++i)
#pragma unroll
        for (int j = 0; j < 2; ++j)
          acc[i][j] = __builtin_amdgcn_mfma_f32_16x16x32_bf16(af[i], bf[j], acc[i][j], 0, 0, 0);
    }
  }

#pragma unroll
  for (int i = 0; i < 2; ++i)
#pragma unroll
    for (int j = 0; j < 2; ++j) {
      const int col = bnb * 64 + wn * 32 + j * 16 + l16;
      const float bias_v = (EPI == 1) ? bias[col] : 0.0f;
#pragma unroll
      for (int r = 0; r < 4; ++r) {
        const int row = bm * 64 + wm * 32 + i * 16 + quad * 4 + r;
        float v = acc[i][j][r] + bias_v;
        const size_t o = (size_t)row * Nout + col;
        if constexpr (EPI == 1) {
          ((float*)outp)[o] = v;
        } else {
          ((u16*)outp)[o] = f2b(0.5f * v);
        }
      }
    }
}

// ---------------- 128x128 tile GEMM (glls staging) ----------------
// MODE 0: split LQKV epilogue; MODE 2: gelu -> bf16
template<int MODE>
__global__ __launch_bounds__(256) void gemm128(
    const u16* __restrict__ A, const u16* __restrict__ W,
    const float* __restrict__ bias0, const float* __restrict__ bias1,
    u16* __restrict__ out0, u16* __restrict__ out1,
    int M, int Nout, int K)
{
  const int tid  = threadIdx.x;
  const int lane = tid & 63, wave = tid >> 6;
  const int quad = lane >> 4, l16 = lane & 15;
  const int wm = wave >> 1, wn = wave & 1;   // 2x2 wave grid, 64x64 per wave
  const int bm = blockIdx.x, bnb = blockIdx.y;

  __shared__ __align__(16) u16 As[128][64];
  __shared__ __align__(16) u16 Ws[128][64];

  f32x4 acc[4][4] = {};

  const int lr = lane >> 3, gs = lane & 7;
  const int g8 = (gs ^ lr) * 8;
  const u16* ab = A + (size_t)(bm  * 128 + wave * 32 + lr) * K + g8;
  const u16* wb = W + (size_t)(bnb * 128 + wave * 32 + lr) * K + g8;

  for (int k0 = 0; k0 < K; k0 += 64) {
    __syncthreads();
#pragma unroll
    for (int c = 0; c < 4; ++c) {
      glds16(ab + (size_t)(c * 8) * K + k0, &As[wave * 32 + c * 8][0]);
      glds16(wb + (size_t)(c * 8) * K + k0, &Ws[wave * 32 + c * 8][0]);
    }
    __syncthreads();
#pragma unroll
    for (int ks = 0; ks < 2; ++ks) {
      const int slot = ((ks * 4 + quad) ^ (l16 & 7)) * 8;
      bf16x8 af[4], bf[4];
#pragma unroll
      for (int am = 0; am < 4; ++am)
        af[am] = *(const bf16x8*)&As[wm * 64 + am * 16 + l16][slot];
#pragma unroll
      for (int bn = 0; bn < 4; ++bn)
        bf[bn] = *(const bf16x8*)&Ws[wn * 64 + bn * 16 + l16][slot];
#pragma unroll
      for (int am = 0; am < 4; ++am)
#pragma unroll
        for (int bn = 0; bn < 4; ++bn)
          acc[am][bn] = __builtin_amdgcn_mfma_f32_16x16x32_bf16(af[am], bf[bn], acc[am][bn], 0, 0, 0);
    }
  }

#pragma unroll
  for (int am = 0; am < 4; ++am)
#pragma unroll
    for (int bn = 0; bn < 4; ++bn) {
      const int col = bnb * 128 + wn * 64 + bn * 16 + l16;
      float bias_v;
      if constexpr (MODE == 0) bias_v = (col < 512) ? bias0[col] : bias1[col - 512];
      else                     bias_v = bias0[col];
#pragma unroll
      for (int r = 0; r < 4; ++r) {
        const int row = bm * 128 + wm * 64 + am * 16 + quad * 4 + r;
        float v = acc[am][bn][r] + bias_v;
        if constexpr (MODE == 0) {
          if (col < 512) out0[(size_t)row * 512 + col] = f2b(v);
          else           out1[(size_t)row * 1536 + (col - 512)] = f2b(v);
        } else {
          float gl = 0.5f * v * (1.0f + erff(v * 0.70710678118654752f));
          out0[(size_t)row * Nout + col] = f2b(gl);
        }
      }
    }
}

// ---------------- CSR build (by destination) ----------------
__global__ __launch_bounds__(256) void scan_kernel(
    const int* __restrict__ deg, int* __restrict__ off, int* __restrict__ cursor)
{
  __shared__ int part[256];
  const int t = threadIdx.x;
  int v[16];
  int s = 0;
#pragma unroll
  for (int i = 0; i < 16; ++i) { v[i] = deg[t * 16 + i]; s += v[i]; }
  part[t] = s;
  __syncthreads();
  for (int d = 1; d < 256; d <<= 1) {
    int val = (t >= d) ? part[t - d] : 0;
    __syncthreads();
    if (t >= d) part[t] += val;
    __syncthreads();
  }
  int prefix = (t == 0) ? 0 : part[t - 1];
#pragma unroll
  for (int i = 0; i < 16; ++i) {
    off[t * 16 + i] = prefix;
    cursor[t * 16 + i] = prefix;
    prefix += v[i];
  }
  if (t == 255) off[4096] = prefix;
}

__global__ __launch_bounds__(256) void fill_kernel(
    const int* __restrict__ ei, int* __restrict__ cursor, int* __restrict__ csr)
{
  const int e = blockIdx.x * 256 + threadIdx.x;
  const int s = ei[e];
  const int d = ei[E_EDGES + e];
  const int p = atomicAdd(&cursor[d], 1);
  csr[p] = s;
}

// ---------------- fused gather-mean (-> Ast[:,0:512] bf16) + V transpose ----
__global__ __launch_bounds__(256) void gather_vtrans(
    const int* __restrict__ off, const int* __restrict__ csr,
    const u16* __restrict__ lh, u16* __restrict__ ast,
    const u16* __restrict__ qkv, u16* __restrict__ vt)
{
  if (blockIdx.y == 0) {              // gather: one wave per dst node
    const int wave = threadIdx.x >> 6, lane = threadIdx.x & 63;
    const int n = blockIdx.x * 4 + wave;
    const int j0 = off[n], j1 = off[n + 1];
    float acc[8] = {};
    for (int j = j0; j < j1; ++j) {
      const int s = csr[j];
      const u16x8 v = *(const u16x8*)(lh + (size_t)s * C_DIM + lane * 8);
#pragma unroll
      for (int i = 0; i < 8; ++i) acc[i] += b2f(v[i]);
    }
    const float inv = 1.0f / fmaxf((float)(j1 - j0), 1.0f);
    u16x8 ob;
#pragma unroll
    for (int i = 0; i < 8; ++i) ob[i] = f2b(acc[i] * inv);
    *(u16x8*)(ast + (size_t)n * 1024 + lane * 8) = ob;
  } else {                            // vtrans: vt[h][d][m] = V[m][h][d]
    if (blockIdx.x >= 512) return;
    const int tid = threadIdx.x;
    const int d = tid & 63, mg = tid >> 6;
    const int h = blockIdx.x >> 6, mt = blockIdx.x & 63;
    const int m0 = mt * 64 + mg * 16;
    u16 buf[16];
#pragma unroll
    for (int i = 0; i < 16; ++i)
      buf[i] = qkv[(size_t)(m0 + i) * 1536 + 1024 + h * 64 + d];
    u16x8 w0, w1;
#pragma unroll
    for (int i = 0; i < 8; ++i) { w0[i] = buf[i]; w1[i] = buf[8 + i]; }
    u16* op = vt + (size_t)(h * 64 + d) * N_NODES + m0;
    *(u16x8*)op = w0;
    *(u16x8*)(op + 8) = w1;
  }
}

// ---------------- flash attention (static max, K-split, glls staging) -------
template<int SPLITS>
__global__ __launch_bounds__(256) void attn_kernel(
    const u16* __restrict__ qkv, const u16* __restrict__ vt,
    float* __restrict__ opart, float* __restrict__ lpart)
{
  const int tid = threadIdx.x, wave = tid >> 6, lane = tid & 63;
  const int quad = lane >> 4, l16 = lane & 15;
  const int h = blockIdx.y, tile = blockIdx.x, split = blockIdx.z;

  __shared__ __align__(16) u16 Ks[64][64];    // K tile, XOR-swizzled
  __shared__ __align__(16) u16 Vts[64][64];   // V^T tile, XOR-swizzled
  __shared__ __align__(16) u16 Ps[128][72];   // P [row][m'] (padded, VALU-written)

  const float QSCALE = 0.18033688011112042f;  // log2(e)/8
  bf16x8 aq[2][2];
#pragma unroll
  for (int mb = 0; mb < 2; ++mb) {
    const int qrow = tile * 128 + wave * 32 + mb * 16 + l16;
    const u16* qp = qkv + (size_t)qrow * 1536 + h * 64 + quad * 8;
    u16x8 q0 = *(const u16x8*)qp;
    u16x8 q1 = *(const u16x8*)(qp + 32);
    u16x8 s0, s1;
#pragma unroll
    for (int i = 0; i < 8; ++i) {
      s0[i] = f2b(b2f(q0[i]) * QSCALE);
      s1[i] = f2b(b2f(q1[i]) * QSCALE);
    }
    aq[mb][0] = __builtin_bit_cast(bf16x8, s0);
    aq[mb][1] = __builtin_bit_cast(bf16x8, s1);
  }

  f32x4 O[2][4] = {};
  float lsum[2][4] = {};

  const int lr = lane >> 3, gs = lane & 7;
  const int g8 = (gs ^ lr) * 8;
  const int R0 = wave * 16 + lr;

  const int mt1 = (split + 1) * (64 / SPLITS);
  for (int mt = split * (64 / SPLITS); mt < mt1; ++mt) {
    __syncthreads();
    glds16(qkv + (size_t)(mt * 64 + R0)     * 1536 + 512 + h * 64 + g8, &Ks[wave * 16][0]);
    glds16(qkv + (size_t)(mt * 64 + R0 + 8) * 1536 + 512 + h * 64 + g8, &Ks[wave * 16 + 8][0]);
    glds16(vt + (size_t)(h * 64 + R0)     * N_NODES + mt * 64 + g8, &Vts[wave * 16][0]);
    glds16(vt + (size_t)(h * 64 + R0 + 8) * N_NODES + mt * 64 + g8, &Vts[wave * 16 + 8][0]);
    __syncthreads();

    // S = (cQ) K^T
    f32x4 s[2][4] = {};
#pragma unroll
    for (int ks = 0; ks < 2; ++ks) {
      const int slot = ((ks * 4 + quad) ^ (l16 & 7)) * 8;
      bf16x8 bk[4];
#pragma unroll
      for (int jn = 0; jn < 4; ++jn)
        bk[jn] = *(const bf16x8*)&Ks[jn * 16 + l16][slot];
#pragma unroll
      for (int mb = 0; mb < 2; ++mb)
#pragma unroll
        for (int jn = 0; jn < 4; ++jn)
          s[mb][jn] = __builtin_amdgcn_mfma_f32_16x16x32_bf16(aq[mb][ks], bk[jn], s[mb][jn], 0, 0, 0);
    }

    // p = exp2(s)
#pragma unroll
    for (int mb = 0; mb < 2; ++mb)
#pragma unroll
      for (int jn = 0; jn < 4; ++jn)
#pragma unroll
        for (int r = 0; r < 4; ++r) {
          float p = __builtin_amdgcn_exp2f(s[mb][jn][r]);
          lsum[mb][r] += p;
          Ps[wave * 32 + mb * 16 + quad * 4 + r][jn * 16 + l16] = f2b_up(p);
        }

    // O += P V
#pragma unroll
    for (int ks = 0; ks < 2; ++ks) {
      const int slot = ((ks * 4 + quad) ^ (l16 & 7)) * 8;
      bf16x8 bv[4];
#pragma unroll
      for (int jd = 0; jd < 4; ++jd)
        bv[jd] = *(const bf16x8*)&Vts[jd * 16 + l16][slot];
#pragma unroll
      for (int mb = 0; mb < 2; ++mb) {
        bf16x8 ap = *(const bf16x8*)&Ps[wave * 32 + mb * 16 + l16][ks * 32 + quad * 8];
#pragma unroll
        for (int jd = 0; jd < 4; ++jd)
          O[mb][jd] = __builtin_amdgcn_mfma_f32_16x16x32_bf16(ap, bv[jd], O[mb][jd], 0, 0, 0);
      }
    }
  }

#pragma unroll
  for (int mb = 0; mb < 2; ++mb)
#pragma unroll
    for (int r = 0; r < 4; ++r)
#pragma unroll
      for (int off = 1; off < 16; off <<= 1)
        lsum[mb][r] += __shfl_xor(lsum[mb][r], off);

#pragma unroll
  for (int mb = 0; mb < 2; ++mb)
#pragma unroll
    for (int r = 0; r < 4; ++r) {
      const int row = tile * 128 + wave * 32 + mb * 16 + quad * 4 + r;
      float* orow = opart + ((size_t)split * N_NODES + row) * C_DIM + h * 64;
#pragma unroll
      for (int jd = 0; jd < 4; ++jd)
        orow[jd * 16 + l16] = O[mb][jd][r];
      if (l16 == 0)
        lpart[((size_t)split * N_NODES + row) * H_HEADS + h] = lsum[mb][r];
    }
}

// combine -> ctx into Ast[:,512:1024] (stride 1024)
template<int SPLITS>
__global__ __launch_bounds__(256) void attn_combine(
    const float* __restrict__ opart, const float* __restrict__ lpart,
    u16* __restrict__ ast)
{
  const size_t base = (size_t)(blockIdx.x * 256 + threadIdx.x) * 8;
  const int row = (int)(base >> 9);
  const int h = (int)((base & 511) >> 6);
  float l = 0.0f;
#pragma unroll
  for (int s = 0; s < SPLITS; ++s)
    l += lpart[(size_t)s * N_NODES * H_HEADS + (size_t)row * H_HEADS + h];
  const float inv = 1.0f / l;
  float o[8] = {};
#pragma unroll
  for (int s = 0; s < SPLITS; ++s) {
    const float* op = opart + (size_t)s * N_NODES * C_DIM + base;
    f32x4 p0 = *(const f32x4*)op;
    f32x4 p1 = *(const f32x4*)(op + 4);
#pragma unroll
    for (int i = 0; i < 4; ++i) { o[i] += p0[i]; o[4 + i] += p1[i]; }
  }
  u16x8 ob;
#pragma unroll
  for (int i = 0; i < 8; ++i) ob[i] = f2b(o[i] * inv);
  *(u16x8*)(ast + (size_t)row * 1024 + 512 + (base & 511)) = ob;
}

// ---------------- LayerNorms (one wave per row) ----------------
__global__ __launch_bounds__(256) void ln1_kernel(
    const float* __restrict__ x, const float* __restrict__ pr,
    const float* __restrict__ g, const float* __restrict__ b,
    u16* __restrict__ hb, float* __restrict__ hf)
{
  const int wave = threadIdx.x >> 6, lane = threadIdx.x & 63;
  const int row = blockIdx.x * 4 + wave;
  const int c0 = lane * 8;
  const size_t base = (size_t)row * C_DIM + c0;
  f32x4 x0 = *(const f32x4*)(x + base);
  f32x4 x1 = *(const f32x4*)(x + base + 4);
  f32x4 p0 = *(const f32x4*)(pr + base);
  f32x4 p1 = *(const f32x4*)(pr + base + 4);
  float v[8];
#pragma unroll
  for (int i = 0; i < 4; ++i) { v[i] = x0[i] + p0[i]; v[4 + i] = x1[i] + p1[i]; }
  float sum = 0, sq = 0;
#pragma unroll
  for (int i = 0; i < 8; ++i) { sum += v[i]; sq += v[i] * v[i]; }
  for (int off = 1; off < 64; off <<= 1) { sum += __shfl_xor(sum, off); sq += __shfl_xor(sq, off); }
  const float mean = sum * (1.0f / C_DIM);
  const float var  = sq * (1.0f / C_DIM) - mean * mean;
  const float rstd = rsqrtf(var + 1e-5f);
  f32x4 g0 = *(const f32x4*)(g + c0), g1 = *(const f32x4*)(g + c0 + 4);
  f32x4 b0 = *(const f32x4*)(b + c0), b1 = *(const f32x4*)(b + c0 + 4);
  u16x8 ob; f32x4 h0, h1;
#pragma unroll
  for (int i = 0; i < 4; ++i) {
    float hv0 = (v[i]     - mean) * rstd * g0[i] + b0[i];
    float hv1 = (v[4 + i] - mean) * rstd * g1[i] + b1[i];
    h0[i] = hv0; h1[i] = hv1;
    ob[i] = f2b(hv0); ob[4 + i] = f2b(hv1);
  }
  *(u16x8*)(hb + base) = ob;
  *(f32x4*)(hf + base) = h0;
  *(f32x4*)(hf + base + 4) = h1;
}

__global__ __launch_bounds__(256) void ln2_kernel(
    const float* __restrict__ a, const float* __restrict__ c,
    const float* __restrict__ g, const float* __restrict__ b,
    float* __restrict__ out)
{
  const int wave = threadIdx.x >> 6, lane = threadIdx.x & 63;
  const int row = blockIdx.x * 4 + wave;
  const int c0 = lane * 8;
  const size_t base = (size_t)row * C_DIM + c0;
  f32x4 a0 = *(const f32x4*)(a + base), a1 = *(const f32x4*)(a + base + 4);
  f32x4 c0v = *(const f32x4*)(c + base), c1v = *(const f32x4*)(c + base + 4);
  float v[8];
#pragma unroll
  for (int i = 0; i < 4; ++i) { v[i] = a0[i] + c0v[i]; v[4 + i] = a1[i] + c1v[i]; }
  float sum = 0, sq = 0;
#pragma unroll
  for (int i = 0; i < 8; ++i) { sum += v[i]; sq += v[i] * v[i]; }
  for (int off = 1; off < 64; off <<= 1) { sum += __shfl_xor(sum, off); sq += __shfl_xor(sq, off); }
  const float mean = sum * (1.0f / C_DIM);
  const float var  = sq * (1.0f / C_DIM) - mean * mean;
  const float rstd = rsqrtf(var + 1e-5f);
  f32x4 g0 = *(const f32x4*)(g + c0), g1 = *(const f32x4*)(g + c0 + 4);
  f32x4 b0 = *(const f32x4*)(b + c0), b1 = *(const f32x4*)(b + c0 + 4);
  f32x4 h0, h1;
#pragma unroll
  for (int i = 0; i < 4; ++i) {
    h0[i] = (v[i]     - mean) * rstd * g0[i] + b0[i];
    h1[i] = (v[4 + i] - mean) * rstd * g1[i] + b1[i];
  }
  *(f32x4*)(out + base) = h0;
  *(f32x4*)(out + base + 4) = h1;
}

// ---------------- launch ----------------
extern "C" void kernel_launch(void* const* d_in, const int* in_sizes, int n_in,
                              void* d_out, int out_size, void* d_ws, size_t ws_size,
                              hipStream_t stream) {
  const float* x          = (const float*)d_in[0];
  const int*   ei         = (const int*)d_in[1];
  const float* local_w    = (const float*)d_in[2];
  const float* local_b    = (const float*)d_in[3];
  const float* in_proj_w  = (const float*)d_in[4];
  const float* in_proj_b  = (const float*)d_in[5];
  const float* attn_out_w = (const float*)d_in[6];
  const float* attn_out_b = (const float*)d_in[7];
  const float* output_w   = (const float*)d_in[8];
  const float* output_b   = (const float*)d_in[9];
  const float* n1g = (const float*)d_in[10];
  const float* n1b = (const float*)d_in[11];
  const float* n2g = (const float*)d_in[12];
  const float* n2b = (const float*)d_in[13];
  const float* ffn_w1 = (const float*)d_in[14];
  const float* ffn_b1 = (const float*)d_in[15];
  const float* ffn_w2 = (const float*)d_in[16];
  const float* ffn_b2 = (const float*)d_in[17];
  float* out = (float*)d_out;

  char* ws = (char*)d_ws;
  size_t o = 0;
  u16* ast = (u16*)(ws + o); o += (size_t)N_NODES * 1024 * 2;             // 8 MB [L|ctx]
  int* deg    = (int*)(ws + o); o += (N_NODES) * 4;
  int* off    = (int*)(ws + o); o += (N_NODES + 16) * 4;
  int* cursor = (int*)(ws + o); o += (N_NODES) * 4;
  int* csr    = (int*)(ws + o); o += (size_t)E_EDGES * 4;
  u16* xb   = (u16*)(ws + o); o += (size_t)N_NODES * C_DIM * 2;           // 4 MB
  u16* wbLQ = (u16*)(ws + o); o += (size_t)4 * C_DIM * C_DIM * 2;         // 2 MB
  u16* wbAT = (u16*)(ws + o); o += (size_t)C_DIM * C_DIM * 2;
  u16* wbO  = (u16*)(ws + o); o += (size_t)C_DIM * C_DIM * 2;
  u16* wcat = (u16*)(ws + o); o += (size_t)C_DIM * 1024 * 2;              // 1 MB
  u16* wbF1 = (u16*)(ws + o); o += (size_t)2 * C_DIM * C_DIM * 2;
  u16* wbF2 = (u16*)(ws + o); o += (size_t)2 * C_DIM * C_DIM * 2;
  float* bprime = (float*)(ws + o); o += 512 * 4;
  u16* local_h   = (u16*)(ws + o); o += (size_t)N_NODES * C_DIM * 2;      // 4 MB
  u16* qkvb      = (u16*)(ws + o); o += (size_t)N_NODES * 3 * C_DIM * 2;  // 12 MB
  u16* hidden_bf = (u16*)(ws + o); o += (size_t)N_NODES * C_DIM * 2;      // 4 MB
  float* hidden_f = (float*)(ws + o); o += (size_t)N_NODES * C_DIM * 4;   // 8 MB
  u16* ff1       = (u16*)(ws + o); o += (size_t)N_NODES * 2 * C_DIM * 2;  // 8 MB
  // aliases (dead ranges reused):
  float* proj = (float*)qkvb;   // qkv dead after attn; proj 8 MB <= 12 MB
  float* ff2  = (float*)ast;    // Ast dead after mixout gemm; 8 MB
  u16*   vt   = xb;             // xb dead after LQKV gemm; 4 MB
  // SPLITS=4 scratch (32.5 MB) past the static region if workspace allows
  float* opart4 = (float*)(ws + o);
  float* lpart4 = (float*)(ws + o + (size_t)4 * N_NODES * C_DIM * 4);
  const size_t need4 = o + (size_t)4 * N_NODES * C_DIM * 4 + (size_t)4 * N_NODES * H_HEADS * 4;
  const bool use4 = (ws_size >= need4);
  // SPLITS=2 fallback: inside hidden_bf..ff1 region (16.25 MB <= 20 MB)
  float* opart2 = (float*)hidden_bf;
  float* lpart2 = opart2 + (size_t)2 * N_NODES * C_DIM;

  (void)hipMemsetAsync(deg, 0, N_NODES * 4, stream);

  // fp32 -> bf16 conversions + hist + bprime
  CvtArgs ca;
  ca.src[0] = x;          ca.dst[0] = xb;   ca.n[0] = N_NODES * C_DIM;
  ca.src[1] = local_w;    ca.dst[1] = wbLQ;                  ca.n[1] = C_DIM * C_DIM;
  ca.src[2] = in_proj_w;  ca.dst[2] = wbLQ + C_DIM * C_DIM;  ca.n[2] = 3 * C_DIM * C_DIM;
  ca.src[3] = attn_out_w; ca.dst[3] = nullptr;               ca.n[3] = C_DIM * C_DIM;
  ca.src[4] = output_w;   ca.dst[4] = wbO;  ca.n[4] = C_DIM * C_DIM;
  ca.src[5] = ffn_w1;     ca.dst[5] = wbF1; ca.n[5] = 2 * C_DIM * C_DIM;
  ca.src[6] = ffn_w2;     ca.dst[6] = wbF2; ca.n[6] = 2 * C_DIM * C_DIM;
  ca.ei = ei; ca.deg = deg;
  ca.wbAT = wbAT; ca.wcat0 = wcat;
  ca.wo_f32 = output_w; ca.ba_f32 = attn_out_b; ca.bo_f32 = output_b;
  ca.bprime = bprime;
  cvt_multi<<<dim3(N_NODES * C_DIM / 2048, 9), 256, 0, stream>>>(ca);

  // CSR build
  scan_kernel<<<1, 256, 0, stream>>>(deg, off, cursor);
  fill_kernel<<<E_EDGES / 256, 256, 0, stream>>>(ei, cursor, csr);

  // Wcat[:,512:1024] = 0.5 * Wo @ Wa   (out = wbO @ wbAT^T, scaled 0.5)
  gemm_bt<5><<<dim3(8, 8), 256, 0, stream>>>(wbO, wbAT, nullptr,
      wcat + 512, 512, 1024, 512);

  // merged local+qkv GEMM: [local_h | qkvb] = xb @ [local_w; in_proj_w]^T
  gemm128<0><<<dim3(32, 16), 256, 0, stream>>>(xb, wbLQ, local_b, in_proj_b,
      local_h, qkvb, N_NODES, 4 * C_DIM, C_DIM);

  // gather-mean (-> Ast[:,0:512]) + V transpose, fused
  gather_vtrans<<<dim3(N_NODES / 4, 2), 256, 0, stream>>>(off, csr, local_h,
      ast, qkvb, vt);

  // attention -> ctx into Ast[:,512:1024]
  if (use4) {
    attn_kernel<4><<<dim3(32, 8, 4), 256, 0, stream>>>(qkvb, vt, opart4, lpart4);
    attn_combine<4><<<N_NODES * C_DIM / 2048, 256, 0, stream>>>(opart4, lpart4, ast);
  } else {
    attn_kernel<2><<<dim3(32, 8, 2), 256, 0, stream>>>(qkvb, vt, opart2, lpart2);
    attn_combine<2><<<N_NODES * C_DIM / 2048, 256, 0, stream>>>(opart2, lpart2, ast);
  }

  // proj = [L|ctx] @ Wcat^T + bprime   (== mixed @ Wo^T + bo, fused)
  gemm_bt<1><<<dim3(64, 8), 256, 0, stream>>>(ast, wcat, bprime, proj,
      N_NODES, C_DIM, 1024);
  ln1_kernel<<<N_NODES / 4, 256, 0, stream>>>(x, proj, n1g, n1b, hidden_bf, hidden_f);

  // FFN
  gemm128<2><<<dim3(32, 8), 256, 0, stream>>>(hidden_bf, wbF1, ffn_b1, nullptr,
      ff1, nullptr, N_NODES, 2 * C_DIM, C_DIM);
  gemm_bt<1><<<dim3(64, 8), 256, 0, stream>>>(ff1, wbF2, ffn_b2, ff2,
      N_NODES, C_DIM, 2 * C_DIM);
  ln2_kernel<<<N_NODES / 4, 256, 0, stream>>>(hidden_f, ff2, n2g, n2b, out);
}

// Round 10
// 295.336 us; speedup vs baseline: 1.0210x; 1.0210x over previous
//
#include <hip/hip_runtime.h>

// SGFormer encoder layer, MI355X gfx950.
// fp32 I/O per reference dtypes; bf16 MFMA internally.
// R2: CSR+gather scatter-mean. R3/4: static-max flash attn, V^T, K-split.
// R5: SPLITS=4, merged LQKV gemm. R7: f2b_up P. R8: glls+XOR-swizzle staging.
// R9 REGRESSED (Wcat algebra: cvt overhead > saved GEMM) -> reverted.
// R10: attn VALU cut: row-sums via ones-MFMA (l = P@1, consistent w/ bf16 P,
//      kills 32 fadds/iter + final shuffles); bf16 split-partials (halves
//      opart traffic); gather+vtrans fused dispatch.

#define N_NODES 4096
#define C_DIM   512
#define H_HEADS 8
#define D_HEAD  64
#define E_EDGES 131072

typedef unsigned short u16;
typedef unsigned int   u32;
typedef u16   u16x8  __attribute__((ext_vector_type(8)));
typedef __bf16 bf16x8 __attribute__((ext_vector_type(8)));
typedef float  f32x4  __attribute__((ext_vector_type(4)));

__device__ __forceinline__ float b2f(u16 u) {
  unsigned int i = ((unsigned int)u) << 16;
  return __builtin_bit_cast(float, i);
}
__device__ __forceinline__ u16 f2b(float f) {
  unsigned int i = __builtin_bit_cast(unsigned int, f);
  i += 0x7fffu + ((i >> 16) & 1u);   // RNE
  return (u16)(i >> 16);
}
__device__ __forceinline__ u16 f2b_up(float f) {   // round-half-up (cheaper)
  unsigned int i = __builtin_bit_cast(unsigned int, f);
  return (u16)((i + 0x8000u) >> 16);
}
// async global->LDS, 16B per lane; LDS dest = wave-uniform base + lane*16
__device__ __forceinline__ void glds16(const u16* g, u16* l) {
  __builtin_amdgcn_global_load_lds(
      (const __attribute__((address_space(1))) void*)g,
      (__attribute__((address_space(3))) void*)l, 16, 0, 0);
}

// ---------------- fp32 -> bf16 batched convert (+ fused hist) ----------------
struct CvtArgs {
  const float* src[7];
  u16* dst[7];
  int n[7];
  const int* ei;
  int* deg;
};

__global__ __launch_bounds__(256) void cvt_multi(CvtArgs a) {
  const int t = blockIdx.y;
  if (t == 7) {                       // fused degree histogram
    if (blockIdx.x >= E_EDGES / 256) return;
    const int e = blockIdx.x * 256 + threadIdx.x;
    atomicAdd(&a.deg[a.ei[E_EDGES + e]], 1);
    return;
  }
  const int i = (blockIdx.x * 256 + threadIdx.x) * 8;
  if (i >= a.n[t]) return;
  const float* s = a.src[t] + i;
  f32x4 v0 = *(const f32x4*)s;
  f32x4 v1 = *(const f32x4*)(s + 4);
  u16x8 o;
  o[0]=f2b(v0[0]); o[1]=f2b(v0[1]); o[2]=f2b(v0[2]); o[3]=f2b(v0[3]);
  o[4]=f2b(v1[0]); o[5]=f2b(v1[1]); o[6]=f2b(v1[2]); o[7]=f2b(v1[3]);
  *(u16x8*)(a.dst[t] + i) = o;
}

// ---------------- 64x64 tile GEMM: out = A[M,K] * W[Nout,K]^T + bias --------
// EPI: 1 = f32 out, 3 = 0.5*local+0.5*v -> bf16
// glls staging, XOR-swizzled LDS (slot = granule ^ (row&7)).
template<int EPI>
__global__ __launch_bounds__(256) void gemm_bt(
    const u16* __restrict__ A, const u16* __restrict__ W,
    const float* __restrict__ bias, void* __restrict__ outp,
    int M, int Nout, int K,
    const float* __restrict__ mloc)
{
  const int tid  = threadIdx.x;
  const int lane = tid & 63, wave = tid >> 6;
  const int quad = lane >> 4, l16 = lane & 15;
  const int wm = wave >> 1, wn = wave & 1;   // 2x2 wave grid, 32x32 per wave
  const int bm = blockIdx.x, bnb = blockIdx.y;

  __shared__ __align__(16) u16 As[64][64];
  __shared__ __align__(16) u16 Ws[64][64];

  f32x4 acc[2][2] = {};

  const int lr = lane >> 3, gs = lane & 7;
  const int g8 = (gs ^ lr) * 8;                  // u16 offset within row
  const u16* a0 = A + (size_t)(bm  * 64 + wave * 16 +     lr) * K + g8;
  const u16* a1 = A + (size_t)(bm  * 64 + wave * 16 + 8 + lr) * K + g8;
  const u16* w0 = W + (size_t)(bnb * 64 + wave * 16 +     lr) * K + g8;
  const u16* w1 = W + (size_t)(bnb * 64 + wave * 16 + 8 + lr) * K + g8;

  for (int k0 = 0; k0 < K; k0 += 64) {
    __syncthreads();                  // prior iter's LDS reads complete
    glds16(a0 + k0, &As[wave * 16][0]);
    glds16(a1 + k0, &As[wave * 16 + 8][0]);
    glds16(w0 + k0, &Ws[wave * 16][0]);
    glds16(w1 + k0, &Ws[wave * 16 + 8][0]);
    __syncthreads();                  // drains vmcnt (glls) before reads
#pragma unroll
    for (int ks = 0; ks < 2; ++ks) {
      const int slot = ((ks * 4 + quad) ^ (l16 & 7)) * 8;
      bf16x8 af[2], bf[2];
      af[0] = *(const bf16x8*)&As[wm * 32 +      l16][slot];
      af[1] = *(const bf16x8*)&As[wm * 32 + 16 + l16][slot];
      bf[0] = *(const bf16x8*)&Ws[wn * 32 +      l16][slot];
      bf[1] = *(const bf16x8*)&Ws[wn * 32 + 16 + l16][slot];
#pragma unroll
      for (int i = 0; i < 2; ++i)
#pragma unroll
        for (int j = 0; j < 2; ++j)
          acc[i][j] = __builtin_amdgcn_mfma_f32_16x16x32_bf16(af[i], bf[j], acc[i][j], 0, 0, 0);
    }
  }

#pragma unroll
  for (int i = 0; i < 2; ++i)
#pragma unroll
    for (int j = 0; j < 2; ++j) {
      const int col = bnb * 64 + wn * 32 + j * 16 + l16;
      const float bias_v = bias[col];
#pragma unroll
      for (int r = 0; r < 4; ++r) {
        const int row = bm * 64 + wm * 32 + i * 16 + quad * 4 + r;
        float v = acc[i][j][r] + bias_v;
        const size_t o = (size_t)row * Nout + col;
        if constexpr (EPI == 1) {
          ((float*)outp)[o] = v;
        } else {
          ((u16*)outp)[o] = f2b(0.5f * mloc[o] + 0.5f * v);
        }
      }
    }
}

// ---------------- 128x128 tile GEMM (glls staging) ----------------
// MODE 0: split LQKV epilogue; MODE 2: gelu -> bf16
template<int MODE>
__global__ __launch_bounds__(256) void gemm128(
    const u16* __restrict__ A, const u16* __restrict__ W,
    const float* __restrict__ bias0, const float* __restrict__ bias1,
    u16* __restrict__ out0, u16* __restrict__ out1,
    int M, int Nout, int K)
{
  const int tid  = threadIdx.x;
  const int lane = tid & 63, wave = tid >> 6;
  const int quad = lane >> 4, l16 = lane & 15;
  const int wm = wave >> 1, wn = wave & 1;   // 2x2 wave grid, 64x64 per wave
  const int bm = blockIdx.x, bnb = blockIdx.y;

  __shared__ __align__(16) u16 As[128][64];
  __shared__ __align__(16) u16 Ws[128][64];

  f32x4 acc[4][4] = {};

  const int lr = lane >> 3, gs = lane & 7;
  const int g8 = (gs ^ lr) * 8;
  const u16* ab = A + (size_t)(bm  * 128 + wave * 32 + lr) * K + g8;
  const u16* wb = W + (size_t)(bnb * 128 + wave * 32 + lr) * K + g8;

  for (int k0 = 0; k0 < K; k0 += 64) {
    __syncthreads();
#pragma unroll
    for (int c = 0; c < 4; ++c) {
      glds16(ab + (size_t)(c * 8) * K + k0, &As[wave * 32 + c * 8][0]);
      glds16(wb + (size_t)(c * 8) * K + k0, &Ws[wave * 32 + c * 8][0]);
    }
    __syncthreads();
#pragma unroll
    for (int ks = 0; ks < 2; ++ks) {
      const int slot = ((ks * 4 + quad) ^ (l16 & 7)) * 8;
      bf16x8 af[4], bf[4];
#pragma unroll
      for (int am = 0; am < 4; ++am)
        af[am] = *(const bf16x8*)&As[wm * 64 + am * 16 + l16][slot];
#pragma unroll
      for (int bn = 0; bn < 4; ++bn)
        bf[bn] = *(const bf16x8*)&Ws[wn * 64 + bn * 16 + l16][slot];
#pragma unroll
      for (int am = 0; am < 4; ++am)
#pragma unroll
        for (int bn = 0; bn < 4; ++bn)
          acc[am][bn] = __builtin_amdgcn_mfma_f32_16x16x32_bf16(af[am], bf[bn], acc[am][bn], 0, 0, 0);
    }
  }

#pragma unroll
  for (int am = 0; am < 4; ++am)
#pragma unroll
    for (int bn = 0; bn < 4; ++bn) {
      const int col = bnb * 128 + wn * 64 + bn * 16 + l16;
      float bias_v;
      if constexpr (MODE == 0) bias_v = (col < 512) ? bias0[col] : bias1[col - 512];
      else                     bias_v = bias0[col];
#pragma unroll
      for (int r = 0; r < 4; ++r) {
        const int row = bm * 128 + wm * 64 + am * 16 + quad * 4 + r;
        float v = acc[am][bn][r] + bias_v;
        if constexpr (MODE == 0) {
          if (col < 512) out0[(size_t)row * 512 + col] = f2b(v);
          else           out1[(size_t)row * 1536 + (col - 512)] = f2b(v);
        } else {
          float gl = 0.5f * v * (1.0f + erff(v * 0.70710678118654752f));
          out0[(size_t)row * Nout + col] = f2b(gl);
        }
      }
    }
}

// ---------------- CSR build (by destination) ----------------
__global__ __launch_bounds__(256) void scan_kernel(
    const int* __restrict__ deg, int* __restrict__ off, int* __restrict__ cursor)
{
  __shared__ int part[256];
  const int t = threadIdx.x;
  int v[16];
  int s = 0;
#pragma unroll
  for (int i = 0; i < 16; ++i) { v[i] = deg[t * 16 + i]; s += v[i]; }
  part[t] = s;
  __syncthreads();
  for (int d = 1; d < 256; d <<= 1) {
    int val = (t >= d) ? part[t - d] : 0;
    __syncthreads();
    if (t >= d) part[t] += val;
    __syncthreads();
  }
  int prefix = (t == 0) ? 0 : part[t - 1];
#pragma unroll
  for (int i = 0; i < 16; ++i) {
    off[t * 16 + i] = prefix;
    cursor[t * 16 + i] = prefix;
    prefix += v[i];
  }
  if (t == 255) off[4096] = prefix;
}

__global__ __launch_bounds__(256) void fill_kernel(
    const int* __restrict__ ei, int* __restrict__ cursor, int* __restrict__ csr)
{
  const int e = blockIdx.x * 256 + threadIdx.x;
  const int s = ei[e];
  const int d = ei[E_EDGES + e];
  const int p = atomicAdd(&cursor[d], 1);
  csr[p] = s;
}

// ---------------- fused gather-mean (fp32 local_out) + V transpose ----------
__global__ __launch_bounds__(256) void gather_vtrans(
    const int* __restrict__ off, const int* __restrict__ csr,
    const u16* __restrict__ lh, float* __restrict__ lo,
    const u16* __restrict__ qkv, u16* __restrict__ vt)
{
  if (blockIdx.y == 0) {              // gather: one wave per dst node
    const int wave = threadIdx.x >> 6, lane = threadIdx.x & 63;
    const int n = blockIdx.x * 4 + wave;
    const int j0 = off[n], j1 = off[n + 1];
    float acc[8] = {};
    for (int j = j0; j < j1; ++j) {
      const int s = csr[j];
      const u16x8 v = *(const u16x8*)(lh + (size_t)s * C_DIM + lane * 8);
#pragma unroll
      for (int i = 0; i < 8; ++i) acc[i] += b2f(v[i]);
    }
    const float inv = 1.0f / fmaxf((float)(j1 - j0), 1.0f);
    f32x4 o0, o1;
#pragma unroll
    for (int i = 0; i < 4; ++i) { o0[i] = acc[i] * inv; o1[i] = acc[4 + i] * inv; }
    float* op = lo + (size_t)n * C_DIM + lane * 8;
    *(f32x4*)op = o0;
    *(f32x4*)(op + 4) = o1;
  } else {                            // vtrans: vt[h][d][m] = V[m][h][d]
    if (blockIdx.x >= 512) return;
    const int tid = threadIdx.x;
    const int d = tid & 63, mg = tid >> 6;
    const int h = blockIdx.x >> 6, mt = blockIdx.x & 63;
    const int m0 = mt * 64 + mg * 16;
    u16 buf[16];
#pragma unroll
    for (int i = 0; i < 16; ++i)
      buf[i] = qkv[(size_t)(m0 + i) * 1536 + 1024 + h * 64 + d];
    u16x8 w0, w1;
#pragma unroll
    for (int i = 0; i < 8; ++i) { w0[i] = buf[i]; w1[i] = buf[8 + i]; }
    u16* op = vt + (size_t)(h * 64 + d) * N_NODES + m0;
    *(u16x8*)op = w0;
    *(u16x8*)(op + 8) = w1;
  }
}

// ---------------- flash attention (static max, K-split, glls staging) -------
// Row sums via ones-MFMA (l = P @ 1, consistent with bf16 P used in PV).
// Split partials stored bf16 (halves opart traffic).
template<int SPLITS>
__global__ __launch_bounds__(256) void attn_kernel(
    const u16* __restrict__ qkv, const u16* __restrict__ vt,
    u16* __restrict__ opart, float* __restrict__ lpart)
{
  const int tid = threadIdx.x, wave = tid >> 6, lane = tid & 63;
  const int quad = lane >> 4, l16 = lane & 15;
  const int h = blockIdx.y, tile = blockIdx.x, split = blockIdx.z;

  __shared__ __align__(16) u16 Ks[64][64];    // K tile, XOR-swizzled
  __shared__ __align__(16) u16 Vts[64][64];   // V^T tile, XOR-swizzled
  __shared__ __align__(16) u16 Ps[128][72];   // P [row][m'] (padded, VALU-written)

  const float QSCALE = 0.18033688011112042f;  // log2(e)/8
  bf16x8 aq[2][2];
#pragma unroll
  for (int mb = 0; mb < 2; ++mb) {
    const int qrow = tile * 128 + wave * 32 + mb * 16 + l16;
    const u16* qp = qkv + (size_t)qrow * 1536 + h * 64 + quad * 8;
    u16x8 q0 = *(const u16x8*)qp;
    u16x8 q1 = *(const u16x8*)(qp + 32);
    u16x8 s0, s1;
#pragma unroll
    for (int i = 0; i < 8; ++i) {
      s0[i] = f2b(b2f(q0[i]) * QSCALE);
      s1[i] = f2b(b2f(q1[i]) * QSCALE);
    }
    aq[mb][0] = __builtin_bit_cast(bf16x8, s0);
    aq[mb][1] = __builtin_bit_cast(bf16x8, s1);
  }

  // all-ones B fragment for row-sum MFMA
  u16x8 ones_u;
#pragma unroll
  for (int i = 0; i < 8; ++i) ones_u[i] = 0x3F80;   // bf16 1.0
  const bf16x8 bones = __builtin_bit_cast(bf16x8, ones_u);

  f32x4 O[2][4] = {};
  f32x4 Lacc[2] = {};   // row-sum accumulator (replicated across l16 cols)

  const int lr = lane >> 3, gs = lane & 7;
  const int g8 = (gs ^ lr) * 8;
  const int R0 = wave * 16 + lr;

  const int mt1 = (split + 1) * (64 / SPLITS);
  for (int mt = split * (64 / SPLITS); mt < mt1; ++mt) {
    __syncthreads();
    glds16(qkv + (size_t)(mt * 64 + R0)     * 1536 + 512 + h * 64 + g8, &Ks[wave * 16][0]);
    glds16(qkv + (size_t)(mt * 64 + R0 + 8) * 1536 + 512 + h * 64 + g8, &Ks[wave * 16 + 8][0]);
    glds16(vt + (size_t)(h * 64 + R0)     * N_NODES + mt * 64 + g8, &Vts[wave * 16][0]);
    glds16(vt + (size_t)(h * 64 + R0 + 8) * N_NODES + mt * 64 + g8, &Vts[wave * 16 + 8][0]);
    __syncthreads();

    // S = (cQ) K^T
    f32x4 s[2][4] = {};
#pragma unroll
    for (int ks = 0; ks < 2; ++ks) {
      const int slot = ((ks * 4 + quad) ^ (l16 & 7)) * 8;
      bf16x8 bk[4];
#pragma unroll
      for (int jn = 0; jn < 4; ++jn)
        bk[jn] = *(const bf16x8*)&Ks[jn * 16 + l16][slot];
#pragma unroll
      for (int mb = 0; mb < 2; ++mb)
#pragma unroll
        for (int jn = 0; jn < 4; ++jn)
          s[mb][jn] = __builtin_amdgcn_mfma_f32_16x16x32_bf16(aq[mb][ks], bk[jn], s[mb][jn], 0, 0, 0);
    }

    // p = exp2(s); store bf16 to Ps (no VALU row-sum — done by ones-MFMA)
#pragma unroll
    for (int mb = 0; mb < 2; ++mb)
#pragma unroll
      for (int jn = 0; jn < 4; ++jn)
#pragma unroll
        for (int r = 0; r < 4; ++r) {
          float p = __builtin_amdgcn_exp2f(s[mb][jn][r]);
          Ps[wave * 32 + mb * 16 + quad * 4 + r][jn * 16 + l16] = f2b_up(p);
        }

    // O += P V ; Lacc += P @ 1
#pragma unroll
    for (int ks = 0; ks < 2; ++ks) {
      const int slot = ((ks * 4 + quad) ^ (l16 & 7)) * 8;
      bf16x8 bv[4];
#pragma unroll
      for (int jd = 0; jd < 4; ++jd)
        bv[jd] = *(const bf16x8*)&Vts[jd * 16 + l16][slot];
#pragma unroll
      for (int mb = 0; mb < 2; ++mb) {
        bf16x8 ap = *(const bf16x8*)&Ps[wave * 32 + mb * 16 + l16][ks * 32 + quad * 8];
#pragma unroll
        for (int jd = 0; jd < 4; ++jd)
          O[mb][jd] = __builtin_amdgcn_mfma_f32_16x16x32_bf16(ap, bv[jd], O[mb][jd], 0, 0, 0);
        Lacc[mb] = __builtin_amdgcn_mfma_f32_16x16x32_bf16(ap, bones, Lacc[mb], 0, 0, 0);
      }
    }
  }

  // write unnormalized partials (bf16) + row sums (already replicated)
#pragma unroll
  for (int mb = 0; mb < 2; ++mb)
#pragma unroll
    for (int r = 0; r < 4; ++r) {
      const int row = tile * 128 + wave * 32 + mb * 16 + quad * 4 + r;
      u16* orow = opart + ((size_t)split * N_NODES + row) * C_DIM + h * 64;
#pragma unroll
      for (int jd = 0; jd < 4; ++jd)
        orow[jd * 16 + l16] = f2b(O[mb][jd][r]);
      if (l16 == 0)
        lpart[((size_t)split * N_NODES + row) * H_HEADS + h] = Lacc[mb][r];
    }
}

template<int SPLITS>
__global__ __launch_bounds__(256) void attn_combine(
    const u16* __restrict__ opart, const float* __restrict__ lpart,
    u16* __restrict__ ctx)
{
  const size_t base = (size_t)(blockIdx.x * 256 + threadIdx.x) * 8;
  const int row = (int)(base >> 9);
  const int h = (int)((base & 511) >> 6);
  float l = 0.0f;
#pragma unroll
  for (int s = 0; s < SPLITS; ++s)
    l += lpart[(size_t)s * N_NODES * H_HEADS + (size_t)row * H_HEADS + h];
  const float inv = 1.0f / l;
  float o[8] = {};
#pragma unroll
  for (int s = 0; s < SPLITS; ++s) {
    const u16x8 p = *(const u16x8*)(opart + (size_t)s * N_NODES * C_DIM + base);
#pragma unroll
    for (int i = 0; i < 8; ++i) o[i] += b2f(p[i]);
  }
  u16x8 ob;
#pragma unroll
  for (int i = 0; i < 8; ++i) ob[i] = f2b(o[i] * inv);
  *(u16x8*)(ctx + base) = ob;
}

// ---------------- LayerNorms (one wave per row) ----------------
__global__ __launch_bounds__(256) void ln1_kernel(
    const float* __restrict__ x, const float* __restrict__ pr,
    const float* __restrict__ g, const float* __restrict__ b,
    u16* __restrict__ hb, float* __restrict__ hf)
{
  const int wave = threadIdx.x >> 6, lane = threadIdx.x & 63;
  const int row = blockIdx.x * 4 + wave;
  const int c0 = lane * 8;
  const size_t base = (size_t)row * C_DIM + c0;
  f32x4 x0 = *(const f32x4*)(x + base);
  f32x4 x1 = *(const f32x4*)(x + base + 4);
  f32x4 p0 = *(const f32x4*)(pr + base);
  f32x4 p1 = *(const f32x4*)(pr + base + 4);
  float v[8];
#pragma unroll
  for (int i = 0; i < 4; ++i) { v[i] = x0[i] + p0[i]; v[4 + i] = x1[i] + p1[i]; }
  float sum = 0, sq = 0;
#pragma unroll
  for (int i = 0; i < 8; ++i) { sum += v[i]; sq += v[i] * v[i]; }
  for (int off = 1; off < 64; off <<= 1) { sum += __shfl_xor(sum, off); sq += __shfl_xor(sq, off); }
  const float mean = sum * (1.0f / C_DIM);
  const float var  = sq * (1.0f / C_DIM) - mean * mean;
  const float rstd = rsqrtf(var + 1e-5f);
  f32x4 g0 = *(const f32x4*)(g + c0), g1 = *(const f32x4*)(g + c0 + 4);
  f32x4 b0 = *(const f32x4*)(b + c0), b1 = *(const f32x4*)(b + c0 + 4);
  u16x8 ob; f32x4 h0, h1;
#pragma unroll
  for (int i = 0; i < 4; ++i) {
    float hv0 = (v[i]     - mean) * rstd * g0[i] + b0[i];
    float hv1 = (v[4 + i] - mean) * rstd * g1[i] + b1[i];
    h0[i] = hv0; h1[i] = hv1;
    ob[i] = f2b(hv0); ob[4 + i] = f2b(hv1);
  }
  *(u16x8*)(hb + base) = ob;
  *(f32x4*)(hf + base) = h0;
  *(f32x4*)(hf + base + 4) = h1;
}

__global__ __launch_bounds__(256) void ln2_kernel(
    const float* __restrict__ a, const float* __restrict__ c,
    const float* __restrict__ g, const float* __restrict__ b,
    float* __restrict__ out)
{
  const int wave = threadIdx.x >> 6, lane = threadIdx.x & 63;
  const int row = blockIdx.x * 4 + wave;
  const int c0 = lane * 8;
  const size_t base = (size_t)row * C_DIM + c0;
  f32x4 a0 = *(const f32x4*)(a + base), a1 = *(const f32x4*)(a + base + 4);
  f32x4 c0v = *(const f32x4*)(c + base), c1v = *(const f32x4*)(c + base + 4);
  float v[8];
#pragma unroll
  for (int i = 0; i < 4; ++i) { v[i] = a0[i] + c0v[i]; v[4 + i] = a1[i] + c1v[i]; }
  float sum = 0, sq = 0;
#pragma unroll
  for (int i = 0; i < 8; ++i) { sum += v[i]; sq += v[i] * v[i]; }
  for (int off = 1; off < 64; off <<= 1) { sum += __shfl_xor(sum, off); sq += __shfl_xor(sq, off); }
  const float mean = sum * (1.0f / C_DIM);
  const float var  = sq * (1.0f / C_DIM) - mean * mean;
  const float rstd = rsqrtf(var + 1e-5f);
  f32x4 g0 = *(const f32x4*)(g + c0), g1 = *(const f32x4*)(g + c0 + 4);
  f32x4 b0 = *(const f32x4*)(b + c0), b1 = *(const f32x4*)(b + c0 + 4);
  f32x4 h0, h1;
#pragma unroll
  for (int i = 0; i < 4; ++i) {
    h0[i] = (v[i]     - mean) * rstd * g0[i] + b0[i];
    h1[i] = (v[4 + i] - mean) * rstd * g1[i] + b1[i];
  }
  *(f32x4*)(out + base) = h0;
  *(f32x4*)(out + base + 4) = h1;
}

// ---------------- launch ----------------
extern "C" void kernel_launch(void* const* d_in, const int* in_sizes, int n_in,
                              void* d_out, int out_size, void* d_ws, size_t ws_size,
                              hipStream_t stream) {
  const float* x          = (const float*)d_in[0];
  const int*   ei         = (const int*)d_in[1];
  const float* local_w    = (const float*)d_in[2];
  const float* local_b    = (const float*)d_in[3];
  const float* in_proj_w  = (const float*)d_in[4];
  const float* in_proj_b  = (const float*)d_in[5];
  const float* attn_out_w = (const float*)d_in[6];
  const float* attn_out_b = (const float*)d_in[7];
  const float* output_w   = (const float*)d_in[8];
  const float* output_b   = (const float*)d_in[9];
  const float* n1g = (const float*)d_in[10];
  const float* n1b = (const float*)d_in[11];
  const float* n2g = (const float*)d_in[12];
  const float* n2b = (const float*)d_in[13];
  const float* ffn_w1 = (const float*)d_in[14];
  const float* ffn_b1 = (const float*)d_in[15];
  const float* ffn_w2 = (const float*)d_in[16];
  const float* ffn_b2 = (const float*)d_in[17];
  float* out = (float*)d_out;

  char* ws = (char*)d_ws;
  size_t o = 0;
  float* local_out = (float*)(ws + o); o += (size_t)N_NODES * C_DIM * 4;  // 8 MB
  int* deg    = (int*)(ws + o); o += (N_NODES) * 4;
  int* off    = (int*)(ws + o); o += (N_NODES + 16) * 4;
  int* cursor = (int*)(ws + o); o += (N_NODES) * 4;
  int* csr    = (int*)(ws + o); o += (size_t)E_EDGES * 4;
  u16* xb   = (u16*)(ws + o); o += (size_t)N_NODES * C_DIM * 2;           // 4 MB
  u16* wbLQ = (u16*)(ws + o); o += (size_t)4 * C_DIM * C_DIM * 2;         // 2 MB
  u16* wbA  = (u16*)(ws + o); o += (size_t)C_DIM * C_DIM * 2;
  u16* wbO  = (u16*)(ws + o); o += (size_t)C_DIM * C_DIM * 2;
  u16* wbF1 = (u16*)(ws + o); o += (size_t)2 * C_DIM * C_DIM * 2;
  u16* wbF2 = (u16*)(ws + o); o += (size_t)2 * C_DIM * C_DIM * 2;
  u16* local_h   = (u16*)(ws + o); o += (size_t)N_NODES * C_DIM * 2;
  u16* qkvb      = (u16*)(ws + o); o += (size_t)N_NODES * 3 * C_DIM * 2;  // 12 MB
  u16* ctxb      = (u16*)(ws + o); o += (size_t)N_NODES * C_DIM * 2;
  u16* mixed     = (u16*)(ws + o); o += (size_t)N_NODES * C_DIM * 2;
  u16* hidden_bf = (u16*)(ws + o); o += (size_t)N_NODES * C_DIM * 2;      // 4 MB
  float* hidden_f = (float*)(ws + o); o += (size_t)N_NODES * C_DIM * 4;   // 8 MB
  u16* ff1       = (u16*)(ws + o); o += (size_t)N_NODES * 2 * C_DIM * 2;  // 8 MB
  // aliases (dead ranges reused):
  float* proj  = (float*)qkvb;       // qkv dead after attn; proj 8 MB <= 12 MB
  float* ff2   = (float*)local_out;  // local_out dead after mix-epilogue gemm
  u16*   vt    = xb;                 // xb dead after LQKV gemm; 4 MB
  // SPLITS=4 bf16 partials (16.25 MB) past static region if workspace allows
  u16* opart4 = (u16*)(ws + o);
  float* lpart4 = (float*)(ws + o + (size_t)4 * N_NODES * C_DIM * 2);
  const size_t need4 = o + (size_t)4 * N_NODES * C_DIM * 2 + (size_t)4 * N_NODES * H_HEADS * 4;
  const bool use4 = (ws_size >= need4);
  // SPLITS=2 fallback: inside hidden_bf..ff1 region (8.25 MB <= 20 MB)
  u16* opart2 = (u16*)hidden_bf;
  float* lpart2 = (float*)(opart2 + (size_t)2 * N_NODES * C_DIM);

  (void)hipMemsetAsync(deg, 0, N_NODES * 4, stream);

  // fp32 -> bf16 conversions (x + weights) + fused degree histogram
  CvtArgs ca;
  ca.src[0] = x;          ca.dst[0] = xb;   ca.n[0] = N_NODES * C_DIM;
  ca.src[1] = local_w;    ca.dst[1] = wbLQ;                  ca.n[1] = C_DIM * C_DIM;
  ca.src[2] = in_proj_w;  ca.dst[2] = wbLQ + C_DIM * C_DIM;  ca.n[2] = 3 * C_DIM * C_DIM;
  ca.src[3] = attn_out_w; ca.dst[3] = wbA;  ca.n[3] = C_DIM * C_DIM;
  ca.src[4] = output_w;   ca.dst[4] = wbO;  ca.n[4] = C_DIM * C_DIM;
  ca.src[5] = ffn_w1;     ca.dst[5] = wbF1; ca.n[5] = 2 * C_DIM * C_DIM;
  ca.src[6] = ffn_w2;     ca.dst[6] = wbF2; ca.n[6] = 2 * C_DIM * C_DIM;
  ca.ei = ei; ca.deg = deg;
  cvt_multi<<<dim3(N_NODES * C_DIM / 2048, 8), 256, 0, stream>>>(ca);

  // CSR build
  scan_kernel<<<1, 256, 0, stream>>>(deg, off, cursor);
  fill_kernel<<<E_EDGES / 256, 256, 0, stream>>>(ei, cursor, csr);

  // merged local+qkv GEMM: [local_h | qkvb] = xb @ [local_w; in_proj_w]^T
  gemm128<0><<<dim3(32, 16), 256, 0, stream>>>(xb, wbLQ, local_b, in_proj_b,
      local_h, qkvb, N_NODES, 4 * C_DIM, C_DIM);

  // gather-mean + V transpose (fused; xb dead after LQKV gemm)
  gather_vtrans<<<dim3(N_NODES / 4, 2), 256, 0, stream>>>(off, csr, local_h,
      local_out, qkvb, vt);

  // attention
  if (use4) {
    attn_kernel<4><<<dim3(32, 8, 4), 256, 0, stream>>>(qkvb, vt, opart4, lpart4);
    attn_combine<4><<<N_NODES * C_DIM / 2048, 256, 0, stream>>>(opart4, lpart4, ctxb);
  } else {
    attn_kernel<2><<<dim3(32, 8, 2), 256, 0, stream>>>(qkvb, vt, opart2, lpart2);
    attn_combine<2><<<N_NODES * C_DIM / 2048, 256, 0, stream>>>(opart2, lpart2, ctxb);
  }

  // mixed = 0.5*local_out + 0.5*(ctx @ attn_out_w^T + b)
  gemm_bt<3><<<dim3(64, 8), 256, 0, stream>>>(ctxb, wbA, attn_out_b, mixed,
      N_NODES, C_DIM, C_DIM, local_out);

  // proj = mixed @ output_w^T + b ; hidden = LN(x + proj)
  gemm_bt<1><<<dim3(64, 8), 256, 0, stream>>>(mixed, wbO, output_b, proj,
      N_NODES, C_DIM, C_DIM, nullptr);
  ln1_kernel<<<N_NODES / 4, 256, 0, stream>>>(x, proj, n1g, n1b, hidden_bf, hidden_f);

  // FFN
  gemm128<2><<<dim3(32, 8), 256, 0, stream>>>(hidden_bf, wbF1, ffn_b1, nullptr,
      ff1, nullptr, N_NODES, 2 * C_DIM, C_DIM);
  gemm_bt<1><<<dim3(64, 8), 256, 0, stream>>>(ff1, wbF2, ffn_b2, ff2,
      N_NODES, C_DIM, 2 * C_DIM, nullptr);
  ln2_kernel<<<N_NODES / 4, 256, 0, stream>>>(hidden_f, ff2, n2g, n2b, out);
}

// Round 11
// 281.494 us; speedup vs baseline: 1.0712x; 1.0492x over previous
//
#include <hip/hip_runtime.h>

// SGFormer encoder layer, MI355X gfx950.
// fp32 I/O per reference dtypes; bf16 MFMA internally.
// R2: CSR+gather scatter-mean. R3/4: static-max flash attn, V^T, K-split.
// R5: SPLITS=4, merged LQKV gemm. R7: f2b_up P. R8: glls+XOR-swizzle staging.
// R9 REGRESSED (Wcat algebra). R10 REGRESSED in attn: ones-MFMA pushed VGPR
//   64->72 -> occupancy cliff (waves halve at vgpr=64). bf16 partials were
//   good (WRITE_SIZE 33->17MB).
// R11: keep bf16 split-partials + fused gather_vtrans; revert row-sums to
//   VALU lsum + 16-lane shuffle (VGPR 64 loop = R8's 57.9us shape).

#define N_NODES 4096
#define C_DIM   512
#define H_HEADS 8
#define D_HEAD  64
#define E_EDGES 131072

typedef unsigned short u16;
typedef unsigned int   u32;
typedef u16   u16x8  __attribute__((ext_vector_type(8)));
typedef __bf16 bf16x8 __attribute__((ext_vector_type(8)));
typedef float  f32x4  __attribute__((ext_vector_type(4)));

__device__ __forceinline__ float b2f(u16 u) {
  unsigned int i = ((unsigned int)u) << 16;
  return __builtin_bit_cast(float, i);
}
__device__ __forceinline__ u16 f2b(float f) {
  unsigned int i = __builtin_bit_cast(unsigned int, f);
  i += 0x7fffu + ((i >> 16) & 1u);   // RNE
  return (u16)(i >> 16);
}
__device__ __forceinline__ u16 f2b_up(float f) {   // round-half-up (cheaper)
  unsigned int i = __builtin_bit_cast(unsigned int, f);
  return (u16)((i + 0x8000u) >> 16);
}
// async global->LDS, 16B per lane; LDS dest = wave-uniform base + lane*16
__device__ __forceinline__ void glds16(const u16* g, u16* l) {
  __builtin_amdgcn_global_load_lds(
      (const __attribute__((address_space(1))) void*)g,
      (__attribute__((address_space(3))) void*)l, 16, 0, 0);
}

// ---------------- fp32 -> bf16 batched convert (+ fused hist) ----------------
struct CvtArgs {
  const float* src[7];
  u16* dst[7];
  int n[7];
  const int* ei;
  int* deg;
};

__global__ __launch_bounds__(256) void cvt_multi(CvtArgs a) {
  const int t = blockIdx.y;
  if (t == 7) {                       // fused degree histogram
    if (blockIdx.x >= E_EDGES / 256) return;
    const int e = blockIdx.x * 256 + threadIdx.x;
    atomicAdd(&a.deg[a.ei[E_EDGES + e]], 1);
    return;
  }
  const int i = (blockIdx.x * 256 + threadIdx.x) * 8;
  if (i >= a.n[t]) return;
  const float* s = a.src[t] + i;
  f32x4 v0 = *(const f32x4*)s;
  f32x4 v1 = *(const f32x4*)(s + 4);
  u16x8 o;
  o[0]=f2b(v0[0]); o[1]=f2b(v0[1]); o[2]=f2b(v0[2]); o[3]=f2b(v0[3]);
  o[4]=f2b(v1[0]); o[5]=f2b(v1[1]); o[6]=f2b(v1[2]); o[7]=f2b(v1[3]);
  *(u16x8*)(a.dst[t] + i) = o;
}

// ---------------- 64x64 tile GEMM: out = A[M,K] * W[Nout,K]^T + bias --------
// EPI: 1 = f32 out, 3 = 0.5*local+0.5*v -> bf16
// glls staging, XOR-swizzled LDS (slot = granule ^ (row&7)).
template<int EPI>
__global__ __launch_bounds__(256) void gemm_bt(
    const u16* __restrict__ A, const u16* __restrict__ W,
    const float* __restrict__ bias, void* __restrict__ outp,
    int M, int Nout, int K,
    const float* __restrict__ mloc)
{
  const int tid  = threadIdx.x;
  const int lane = tid & 63, wave = tid >> 6;
  const int quad = lane >> 4, l16 = lane & 15;
  const int wm = wave >> 1, wn = wave & 1;   // 2x2 wave grid, 32x32 per wave
  const int bm = blockIdx.x, bnb = blockIdx.y;

  __shared__ __align__(16) u16 As[64][64];
  __shared__ __align__(16) u16 Ws[64][64];

  f32x4 acc[2][2] = {};

  const int lr = lane >> 3, gs = lane & 7;
  const int g8 = (gs ^ lr) * 8;                  // u16 offset within row
  const u16* a0 = A + (size_t)(bm  * 64 + wave * 16 +     lr) * K + g8;
  const u16* a1 = A + (size_t)(bm  * 64 + wave * 16 + 8 + lr) * K + g8;
  const u16* w0 = W + (size_t)(bnb * 64 + wave * 16 +     lr) * K + g8;
  const u16* w1 = W + (size_t)(bnb * 64 + wave * 16 + 8 + lr) * K + g8;

  for (int k0 = 0; k0 < K; k0 += 64) {
    __syncthreads();                  // prior iter's LDS reads complete
    glds16(a0 + k0, &As[wave * 16][0]);
    glds16(a1 + k0, &As[wave * 16 + 8][0]);
    glds16(w0 + k0, &Ws[wave * 16][0]);
    glds16(w1 + k0, &Ws[wave * 16 + 8][0]);
    __syncthreads();                  // drains vmcnt (glls) before reads
#pragma unroll
    for (int ks = 0; ks < 2; ++ks) {
      const int slot = ((ks * 4 + quad) ^ (l16 & 7)) * 8;
      bf16x8 af[2], bf[2];
      af[0] = *(const bf16x8*)&As[wm * 32 +      l16][slot];
      af[1] = *(const bf16x8*)&As[wm * 32 + 16 + l16][slot];
      bf[0] = *(const bf16x8*)&Ws[wn * 32 +      l16][slot];
      bf[1] = *(const bf16x8*)&Ws[wn * 32 + 16 + l16][slot];
#pragma unroll
      for (int i = 0; i < 2; ++i)
#pragma unroll
        for (int j = 0; j < 2; ++j)
          acc[i][j] = __builtin_amdgcn_mfma_f32_16x16x32_bf16(af[i], bf[j], acc[i][j], 0, 0, 0);
    }
  }

#pragma unroll
  for (int i = 0; i < 2; ++i)
#pragma unroll
    for (int j = 0; j < 2; ++j) {
      const int col = bnb * 64 + wn * 32 + j * 16 + l16;
      const float bias_v = bias[col];
#pragma unroll
      for (int r = 0; r < 4; ++r) {
        const int row = bm * 64 + wm * 32 + i * 16 + quad * 4 + r;
        float v = acc[i][j][r] + bias_v;
        const size_t o = (size_t)row * Nout + col;
        if constexpr (EPI == 1) {
          ((float*)outp)[o] = v;
        } else {
          ((u16*)outp)[o] = f2b(0.5f * mloc[o] + 0.5f * v);
        }
      }
    }
}

// ---------------- 128x128 tile GEMM (glls staging) ----------------
// MODE 0: split LQKV epilogue; MODE 2: gelu -> bf16
template<int MODE>
__global__ __launch_bounds__(256) void gemm128(
    const u16* __restrict__ A, const u16* __restrict__ W,
    const float* __restrict__ bias0, const float* __restrict__ bias1,
    u16* __restrict__ out0, u16* __restrict__ out1,
    int M, int Nout, int K)
{
  const int tid  = threadIdx.x;
  const int lane = tid & 63, wave = tid >> 6;
  const int quad = lane >> 4, l16 = lane & 15;
  const int wm = wave >> 1, wn = wave & 1;   // 2x2 wave grid, 64x64 per wave
  const int bm = blockIdx.x, bnb = blockIdx.y;

  __shared__ __align__(16) u16 As[128][64];
  __shared__ __align__(16) u16 Ws[128][64];

  f32x4 acc[4][4] = {};

  const int lr = lane >> 3, gs = lane & 7;
  const int g8 = (gs ^ lr) * 8;
  const u16* ab = A + (size_t)(bm  * 128 + wave * 32 + lr) * K + g8;
  const u16* wb = W + (size_t)(bnb * 128 + wave * 32 + lr) * K + g8;

  for (int k0 = 0; k0 < K; k0 += 64) {
    __syncthreads();
#pragma unroll
    for (int c = 0; c < 4; ++c) {
      glds16(ab + (size_t)(c * 8) * K + k0, &As[wave * 32 + c * 8][0]);
      glds16(wb + (size_t)(c * 8) * K + k0, &Ws[wave * 32 + c * 8][0]);
    }
    __syncthreads();
#pragma unroll
    for (int ks = 0; ks < 2; ++ks) {
      const int slot = ((ks * 4 + quad) ^ (l16 & 7)) * 8;
      bf16x8 af[4], bf[4];
#pragma unroll
      for (int am = 0; am < 4; ++am)
        af[am] = *(const bf16x8*)&As[wm * 64 + am * 16 + l16][slot];
#pragma unroll
      for (int bn = 0; bn < 4; ++bn)
        bf[bn] = *(const bf16x8*)&Ws[wn * 64 + bn * 16 + l16][slot];
#pragma unroll
      for (int am = 0; am < 4; ++am)
#pragma unroll
        for (int bn = 0; bn < 4; ++bn)
          acc[am][bn] = __builtin_amdgcn_mfma_f32_16x16x32_bf16(af[am], bf[bn], acc[am][bn], 0, 0, 0);
    }
  }

#pragma unroll
  for (int am = 0; am < 4; ++am)
#pragma unroll
    for (int bn = 0; bn < 4; ++bn) {
      const int col = bnb * 128 + wn * 64 + bn * 16 + l16;
      float bias_v;
      if constexpr (MODE == 0) bias_v = (col < 512) ? bias0[col] : bias1[col - 512];
      else                     bias_v = bias0[col];
#pragma unroll
      for (int r = 0; r < 4; ++r) {
        const int row = bm * 128 + wm * 64 + am * 16 + quad * 4 + r;
        float v = acc[am][bn][r] + bias_v;
        if constexpr (MODE == 0) {
          if (col < 512) out0[(size_t)row * 512 + col] = f2b(v);
          else           out1[(size_t)row * 1536 + (col - 512)] = f2b(v);
        } else {
          float gl = 0.5f * v * (1.0f + erff(v * 0.70710678118654752f));
          out0[(size_t)row * Nout + col] = f2b(gl);
        }
      }
    }
}

// ---------------- CSR build (by destination) ----------------
__global__ __launch_bounds__(256) void scan_kernel(
    const int* __restrict__ deg, int* __restrict__ off, int* __restrict__ cursor)
{
  __shared__ int part[256];
  const int t = threadIdx.x;
  int v[16];
  int s = 0;
#pragma unroll
  for (int i = 0; i < 16; ++i) { v[i] = deg[t * 16 + i]; s += v[i]; }
  part[t] = s;
  __syncthreads();
  for (int d = 1; d < 256; d <<= 1) {
    int val = (t >= d) ? part[t - d] : 0;
    __syncthreads();
    if (t >= d) part[t] += val;
    __syncthreads();
  }
  int prefix = (t == 0) ? 0 : part[t - 1];
#pragma unroll
  for (int i = 0; i < 16; ++i) {
    off[t * 16 + i] = prefix;
    cursor[t * 16 + i] = prefix;
    prefix += v[i];
  }
  if (t == 255) off[4096] = prefix;
}

__global__ __launch_bounds__(256) void fill_kernel(
    const int* __restrict__ ei, int* __restrict__ cursor, int* __restrict__ csr)
{
  const int e = blockIdx.x * 256 + threadIdx.x;
  const int s = ei[e];
  const int d = ei[E_EDGES + e];
  const int p = atomicAdd(&cursor[d], 1);
  csr[p] = s;
}

// ---------------- fused gather-mean (fp32 local_out) + V transpose ----------
__global__ __launch_bounds__(256) void gather_vtrans(
    const int* __restrict__ off, const int* __restrict__ csr,
    const u16* __restrict__ lh, float* __restrict__ lo,
    const u16* __restrict__ qkv, u16* __restrict__ vt)
{
  if (blockIdx.y == 0) {              // gather: one wave per dst node
    const int wave = threadIdx.x >> 6, lane = threadIdx.x & 63;
    const int n = blockIdx.x * 4 + wave;
    const int j0 = off[n], j1 = off[n + 1];
    float acc[8] = {};
    for (int j = j0; j < j1; ++j) {
      const int s = csr[j];
      const u16x8 v = *(const u16x8*)(lh + (size_t)s * C_DIM + lane * 8);
#pragma unroll
      for (int i = 0; i < 8; ++i) acc[i] += b2f(v[i]);
    }
    const float inv = 1.0f / fmaxf((float)(j1 - j0), 1.0f);
    f32x4 o0, o1;
#pragma unroll
    for (int i = 0; i < 4; ++i) { o0[i] = acc[i] * inv; o1[i] = acc[4 + i] * inv; }
    float* op = lo + (size_t)n * C_DIM + lane * 8;
    *(f32x4*)op = o0;
    *(f32x4*)(op + 4) = o1;
  } else {                            // vtrans: vt[h][d][m] = V[m][h][d]
    if (blockIdx.x >= 512) return;
    const int tid = threadIdx.x;
    const int d = tid & 63, mg = tid >> 6;
    const int h = blockIdx.x >> 6, mt = blockIdx.x & 63;
    const int m0 = mt * 64 + mg * 16;
    u16 buf[16];
#pragma unroll
    for (int i = 0; i < 16; ++i)
      buf[i] = qkv[(size_t)(m0 + i) * 1536 + 1024 + h * 64 + d];
    u16x8 w0, w1;
#pragma unroll
    for (int i = 0; i < 8; ++i) { w0[i] = buf[i]; w1[i] = buf[8 + i]; }
    u16* op = vt + (size_t)(h * 64 + d) * N_NODES + m0;
    *(u16x8*)op = w0;
    *(u16x8*)(op + 8) = w1;
  }
}

// ---------------- flash attention (static max, K-split, glls staging) -------
// VALU lsum + 16-lane shuffle (VGPR 64 loop); bf16 split partials.
template<int SPLITS>
__global__ __launch_bounds__(256) void attn_kernel(
    const u16* __restrict__ qkv, const u16* __restrict__ vt,
    u16* __restrict__ opart, float* __restrict__ lpart)
{
  const int tid = threadIdx.x, wave = tid >> 6, lane = tid & 63;
  const int quad = lane >> 4, l16 = lane & 15;
  const int h = blockIdx.y, tile = blockIdx.x, split = blockIdx.z;

  __shared__ __align__(16) u16 Ks[64][64];    // K tile, XOR-swizzled
  __shared__ __align__(16) u16 Vts[64][64];   // V^T tile, XOR-swizzled
  __shared__ __align__(16) u16 Ps[128][72];   // P [row][m'] (padded, VALU-written)

  const float QSCALE = 0.18033688011112042f;  // log2(e)/8
  bf16x8 aq[2][2];
#pragma unroll
  for (int mb = 0; mb < 2; ++mb) {
    const int qrow = tile * 128 + wave * 32 + mb * 16 + l16;
    const u16* qp = qkv + (size_t)qrow * 1536 + h * 64 + quad * 8;
    u16x8 q0 = *(const u16x8*)qp;
    u16x8 q1 = *(const u16x8*)(qp + 32);
    u16x8 s0, s1;
#pragma unroll
    for (int i = 0; i < 8; ++i) {
      s0[i] = f2b(b2f(q0[i]) * QSCALE);
      s1[i] = f2b(b2f(q1[i]) * QSCALE);
    }
    aq[mb][0] = __builtin_bit_cast(bf16x8, s0);
    aq[mb][1] = __builtin_bit_cast(bf16x8, s1);
  }

  f32x4 O[2][4] = {};
  float lsum[2][4] = {};   // per-lane partial row sums

  const int lr = lane >> 3, gs = lane & 7;
  const int g8 = (gs ^ lr) * 8;
  const int R0 = wave * 16 + lr;

  const int mt1 = (split + 1) * (64 / SPLITS);
  for (int mt = split * (64 / SPLITS); mt < mt1; ++mt) {
    __syncthreads();
    glds16(qkv + (size_t)(mt * 64 + R0)     * 1536 + 512 + h * 64 + g8, &Ks[wave * 16][0]);
    glds16(qkv + (size_t)(mt * 64 + R0 + 8) * 1536 + 512 + h * 64 + g8, &Ks[wave * 16 + 8][0]);
    glds16(vt + (size_t)(h * 64 + R0)     * N_NODES + mt * 64 + g8, &Vts[wave * 16][0]);
    glds16(vt + (size_t)(h * 64 + R0 + 8) * N_NODES + mt * 64 + g8, &Vts[wave * 16 + 8][0]);
    __syncthreads();

    // S = (cQ) K^T
    f32x4 s[2][4] = {};
#pragma unroll
    for (int ks = 0; ks < 2; ++ks) {
      const int slot = ((ks * 4 + quad) ^ (l16 & 7)) * 8;
      bf16x8 bk[4];
#pragma unroll
      for (int jn = 0; jn < 4; ++jn)
        bk[jn] = *(const bf16x8*)&Ks[jn * 16 + l16][slot];
#pragma unroll
      for (int mb = 0; mb < 2; ++mb)
#pragma unroll
        for (int jn = 0; jn < 4; ++jn)
          s[mb][jn] = __builtin_amdgcn_mfma_f32_16x16x32_bf16(aq[mb][ks], bk[jn], s[mb][jn], 0, 0, 0);
    }

    // p = exp2(s); accumulate per-lane partial sums; half-up bf16 store
#pragma unroll
    for (int mb = 0; mb < 2; ++mb)
#pragma unroll
      for (int jn = 0; jn < 4; ++jn)
#pragma unroll
        for (int r = 0; r < 4; ++r) {
          float p = __builtin_amdgcn_exp2f(s[mb][jn][r]);
          lsum[mb][r] += p;
          Ps[wave * 32 + mb * 16 + quad * 4 + r][jn * 16 + l16] = f2b_up(p);
        }
    // no barrier: Ps rows are wave-private; lgkmcnt ordering handles RAW

    // O += P V
#pragma unroll
    for (int ks = 0; ks < 2; ++ks) {
      const int slot = ((ks * 4 + quad) ^ (l16 & 7)) * 8;
      bf16x8 bv[4];
#pragma unroll
      for (int jd = 0; jd < 4; ++jd)
        bv[jd] = *(const bf16x8*)&Vts[jd * 16 + l16][slot];
#pragma unroll
      for (int mb = 0; mb < 2; ++mb) {
        bf16x8 ap = *(const bf16x8*)&Ps[wave * 32 + mb * 16 + l16][ks * 32 + quad * 8];
#pragma unroll
        for (int jd = 0; jd < 4; ++jd)
          O[mb][jd] = __builtin_amdgcn_mfma_f32_16x16x32_bf16(ap, bv[jd], O[mb][jd], 0, 0, 0);
      }
    }
  }

  // one-time 16-lane reduce of row-sum partials
#pragma unroll
  for (int mb = 0; mb < 2; ++mb)
#pragma unroll
    for (int r = 0; r < 4; ++r)
#pragma unroll
      for (int off = 1; off < 16; off <<= 1)
        lsum[mb][r] += __shfl_xor(lsum[mb][r], off);

  // write unnormalized partials (bf16) + row sums
#pragma unroll
  for (int mb = 0; mb < 2; ++mb)
#pragma unroll
    for (int r = 0; r < 4; ++r) {
      const int row = tile * 128 + wave * 32 + mb * 16 + quad * 4 + r;
      u16* orow = opart + ((size_t)split * N_NODES + row) * C_DIM + h * 64;
#pragma unroll
      for (int jd = 0; jd < 4; ++jd)
        orow[jd * 16 + l16] = f2b(O[mb][jd][r]);
      if (l16 == 0)
        lpart[((size_t)split * N_NODES + row) * H_HEADS + h] = lsum[mb][r];
    }
}

template<int SPLITS>
__global__ __launch_bounds__(256) void attn_combine(
    const u16* __restrict__ opart, const float* __restrict__ lpart,
    u16* __restrict__ ctx)
{
  const size_t base = (size_t)(blockIdx.x * 256 + threadIdx.x) * 8;
  const int row = (int)(base >> 9);
  const int h = (int)((base & 511) >> 6);
  float l = 0.0f;
#pragma unroll
  for (int s = 0; s < SPLITS; ++s)
    l += lpart[(size_t)s * N_NODES * H_HEADS + (size_t)row * H_HEADS + h];
  const float inv = 1.0f / l;
  float o[8] = {};
#pragma unroll
  for (int s = 0; s < SPLITS; ++s) {
    const u16x8 p = *(const u16x8*)(opart + (size_t)s * N_NODES * C_DIM + base);
#pragma unroll
    for (int i = 0; i < 8; ++i) o[i] += b2f(p[i]);
  }
  u16x8 ob;
#pragma unroll
  for (int i = 0; i < 8; ++i) ob[i] = f2b(o[i] * inv);
  *(u16x8*)(ctx + base) = ob;
}

// ---------------- LayerNorms (one wave per row) ----------------
__global__ __launch_bounds__(256) void ln1_kernel(
    const float* __restrict__ x, const float* __restrict__ pr,
    const float* __restrict__ g, const float* __restrict__ b,
    u16* __restrict__ hb, float* __restrict__ hf)
{
  const int wave = threadIdx.x >> 6, lane = threadIdx.x & 63;
  const int row = blockIdx.x * 4 + wave;
  const int c0 = lane * 8;
  const size_t base = (size_t)row * C_DIM + c0;
  f32x4 x0 = *(const f32x4*)(x + base);
  f32x4 x1 = *(const f32x4*)(x + base + 4);
  f32x4 p0 = *(const f32x4*)(pr + base);
  f32x4 p1 = *(const f32x4*)(pr + base + 4);
  float v[8];
#pragma unroll
  for (int i = 0; i < 4; ++i) { v[i] = x0[i] + p0[i]; v[4 + i] = x1[i] + p1[i]; }
  float sum = 0, sq = 0;
#pragma unroll
  for (int i = 0; i < 8; ++i) { sum += v[i]; sq += v[i] * v[i]; }
  for (int off = 1; off < 64; off <<= 1) { sum += __shfl_xor(sum, off); sq += __shfl_xor(sq, off); }
  const float mean = sum * (1.0f / C_DIM);
  const float var  = sq * (1.0f / C_DIM) - mean * mean;
  const float rstd = rsqrtf(var + 1e-5f);
  f32x4 g0 = *(const f32x4*)(g + c0), g1 = *(const f32x4*)(g + c0 + 4);
  f32x4 b0 = *(const f32x4*)(b + c0), b1 = *(const f32x4*)(b + c0 + 4);
  u16x8 ob; f32x4 h0, h1;
#pragma unroll
  for (int i = 0; i < 4; ++i) {
    float hv0 = (v[i]     - mean) * rstd * g0[i] + b0[i];
    float hv1 = (v[4 + i] - mean) * rstd * g1[i] + b1[i];
    h0[i] = hv0; h1[i] = hv1;
    ob[i] = f2b(hv0); ob[4 + i] = f2b(hv1);
  }
  *(u16x8*)(hb + base) = ob;
  *(f32x4*)(hf + base) = h0;
  *(f32x4*)(hf + base + 4) = h1;
}

__global__ __launch_bounds__(256) void ln2_kernel(
    const float* __restrict__ a, const float* __restrict__ c,
    const float* __restrict__ g, const float* __restrict__ b,
    float* __restrict__ out)
{
  const int wave = threadIdx.x >> 6, lane = threadIdx.x & 63;
  const int row = blockIdx.x * 4 + wave;
  const int c0 = lane * 8;
  const size_t base = (size_t)row * C_DIM + c0;
  f32x4 a0 = *(const f32x4*)(a + base), a1 = *(const f32x4*)(a + base + 4);
  f32x4 c0v = *(const f32x4*)(c + base), c1v = *(const f32x4*)(c + base + 4);
  float v[8];
#pragma unroll
  for (int i = 0; i < 4; ++i) { v[i] = a0[i] + c0v[i]; v[4 + i] = a1[i] + c1v[i]; }
  float sum = 0, sq = 0;
#pragma unroll
  for (int i = 0; i < 8; ++i) { sum += v[i]; sq += v[i] * v[i]; }
  for (int off = 1; off < 64; off <<= 1) { sum += __shfl_xor(sum, off); sq += __shfl_xor(sq, off); }
  const float mean = sum * (1.0f / C_DIM);
  const float var  = sq * (1.0f / C_DIM) - mean * mean;
  const float rstd = rsqrtf(var + 1e-5f);
  f32x4 g0 = *(const f32x4*)(g + c0), g1 = *(const f32x4*)(g + c0 + 4);
  f32x4 b0 = *(const f32x4*)(b + c0), b1 = *(const f32x4*)(b + c0 + 4);
  f32x4 h0, h1;
#pragma unroll
  for (int i = 0; i < 4; ++i) {
    h0[i] = (v[i]     - mean) * rstd * g0[i] + b0[i];
    h1[i] = (v[4 + i] - mean) * rstd * g1[i] + b1[i];
  }
  *(f32x4*)(out + base) = h0;
  *(f32x4*)(out + base + 4) = h1;
}

// ---------------- launch ----------------
extern "C" void kernel_launch(void* const* d_in, const int* in_sizes, int n_in,
                              void* d_out, int out_size, void* d_ws, size_t ws_size,
                              hipStream_t stream) {
  const float* x          = (const float*)d_in[0];
  const int*   ei         = (const int*)d_in[1];
  const float* local_w    = (const float*)d_in[2];
  const float* local_b    = (const float*)d_in[3];
  const float* in_proj_w  = (const float*)d_in[4];
  const float* in_proj_b  = (const float*)d_in[5];
  const float* attn_out_w = (const float*)d_in[6];
  const float* attn_out_b = (const float*)d_in[7];
  const float* output_w   = (const float*)d_in[8];
  const float* output_b   = (const float*)d_in[9];
  const float* n1g = (const float*)d_in[10];
  const float* n1b = (const float*)d_in[11];
  const float* n2g = (const float*)d_in[12];
  const float* n2b = (const float*)d_in[13];
  const float* ffn_w1 = (const float*)d_in[14];
  const float* ffn_b1 = (const float*)d_in[15];
  const float* ffn_w2 = (const float*)d_in[16];
  const float* ffn_b2 = (const float*)d_in[17];
  float* out = (float*)d_out;

  char* ws = (char*)d_ws;
  size_t o = 0;
  float* local_out = (float*)(ws + o); o += (size_t)N_NODES * C_DIM * 4;  // 8 MB
  int* deg    = (int*)(ws + o); o += (N_NODES) * 4;
  int* off    = (int*)(ws + o); o += (N_NODES + 16) * 4;
  int* cursor = (int*)(ws + o); o += (N_NODES) * 4;
  int* csr    = (int*)(ws + o); o += (size_t)E_EDGES * 4;
  u16* xb   = (u16*)(ws + o); o += (size_t)N_NODES * C_DIM * 2;           // 4 MB
  u16* wbLQ = (u16*)(ws + o); o += (size_t)4 * C_DIM * C_DIM * 2;         // 2 MB
  u16* wbA  = (u16*)(ws + o); o += (size_t)C_DIM * C_DIM * 2;
  u16* wbO  = (u16*)(ws + o); o += (size_t)C_DIM * C_DIM * 2;
  u16* wbF1 = (u16*)(ws + o); o += (size_t)2 * C_DIM * C_DIM * 2;
  u16* wbF2 = (u16*)(ws + o); o += (size_t)2 * C_DIM * C_DIM * 2;
  u16* local_h   = (u16*)(ws + o); o += (size_t)N_NODES * C_DIM * 2;
  u16* qkvb      = (u16*)(ws + o); o += (size_t)N_NODES * 3 * C_DIM * 2;  // 12 MB
  u16* ctxb      = (u16*)(ws + o); o += (size_t)N_NODES * C_DIM * 2;
  u16* mixed     = (u16*)(ws + o); o += (size_t)N_NODES * C_DIM * 2;
  u16* hidden_bf = (u16*)(ws + o); o += (size_t)N_NODES * C_DIM * 2;      // 4 MB
  float* hidden_f = (float*)(ws + o); o += (size_t)N_NODES * C_DIM * 4;   // 8 MB
  u16* ff1       = (u16*)(ws + o); o += (size_t)N_NODES * 2 * C_DIM * 2;  // 8 MB
  // aliases (dead ranges reused):
  float* proj  = (float*)qkvb;       // qkv dead after attn; proj 8 MB <= 12 MB
  float* ff2   = (float*)local_out;  // local_out dead after mix-epilogue gemm
  u16*   vt    = xb;                 // xb dead after LQKV gemm; 4 MB
  // SPLITS=4 bf16 partials (16.25 MB) past static region if workspace allows
  u16* opart4 = (u16*)(ws + o);
  float* lpart4 = (float*)(ws + o + (size_t)4 * N_NODES * C_DIM * 2);
  const size_t need4 = o + (size_t)4 * N_NODES * C_DIM * 2 + (size_t)4 * N_NODES * H_HEADS * 4;
  const bool use4 = (ws_size >= need4);
  // SPLITS=2 fallback: inside hidden_bf..ff1 region (8.25 MB <= 20 MB)
  u16* opart2 = (u16*)hidden_bf;
  float* lpart2 = (float*)(opart2 + (size_t)2 * N_NODES * C_DIM);

  (void)hipMemsetAsync(deg, 0, N_NODES * 4, stream);

  // fp32 -> bf16 conversions (x + weights) + fused degree histogram
  CvtArgs ca;
  ca.src[0] = x;          ca.dst[0] = xb;   ca.n[0] = N_NODES * C_DIM;
  ca.src[1] = local_w;    ca.dst[1] = wbLQ;                  ca.n[1] = C_DIM * C_DIM;
  ca.src[2] = in_proj_w;  ca.dst[2] = wbLQ + C_DIM * C_DIM;  ca.n[2] = 3 * C_DIM * C_DIM;
  ca.src[3] = attn_out_w; ca.dst[3] = wbA;  ca.n[3] = C_DIM * C_DIM;
  ca.src[4] = output_w;   ca.dst[4] = wbO;  ca.n[4] = C_DIM * C_DIM;
  ca.src[5] = ffn_w1;     ca.dst[5] = wbF1; ca.n[5] = 2 * C_DIM * C_DIM;
  ca.src[6] = ffn_w2;     ca.dst[6] = wbF2; ca.n[6] = 2 * C_DIM * C_DIM;
  ca.ei = ei; ca.deg = deg;
  cvt_multi<<<dim3(N_NODES * C_DIM / 2048, 8), 256, 0, stream>>>(ca);

  // CSR build
  scan_kernel<<<1, 256, 0, stream>>>(deg, off, cursor);
  fill_kernel<<<E_EDGES / 256, 256, 0, stream>>>(ei, cursor, csr);

  // merged local+qkv GEMM: [local_h | qkvb] = xb @ [local_w; in_proj_w]^T
  gemm128<0><<<dim3(32, 16), 256, 0, stream>>>(xb, wbLQ, local_b, in_proj_b,
      local_h, qkvb, N_NODES, 4 * C_DIM, C_DIM);

  // gather-mean + V transpose (fused; xb dead after LQKV gemm)
  gather_vtrans<<<dim3(N_NODES / 4, 2), 256, 0, stream>>>(off, csr, local_h,
      local_out, qkvb, vt);

  // attention
  if (use4) {
    attn_kernel<4><<<dim3(32, 8, 4), 256, 0, stream>>>(qkvb, vt, opart4, lpart4);
    attn_combine<4><<<N_NODES * C_DIM / 2048, 256, 0, stream>>>(opart4, lpart4, ctxb);
  } else {
    attn_kernel<2><<<dim3(32, 8, 2), 256, 0, stream>>>(qkvb, vt, opart2, lpart2);
    attn_combine<2><<<N_NODES * C_DIM / 2048, 256, 0, stream>>>(opart2, lpart2, ctxb);
  }

  // mixed = 0.5*local_out + 0.5*(ctx @ attn_out_w^T + b)
  gemm_bt<3><<<dim3(64, 8), 256, 0, stream>>>(ctxb, wbA, attn_out_b, mixed,
      N_NODES, C_DIM, C_DIM, local_out);

  // proj = mixed @ output_w^T + b ; hidden = LN(x + proj)
  gemm_bt<1><<<dim3(64, 8), 256, 0, stream>>>(mixed, wbO, output_b, proj,
      N_NODES, C_DIM, C_DIM, nullptr);
  ln1_kernel<<<N_NODES / 4, 256, 0, stream>>>(x, proj, n1g, n1b, hidden_bf, hidden_f);

  // FFN
  gemm128<2><<<dim3(32, 8), 256, 0, stream>>>(hidden_bf, wbF1, ffn_b1, nullptr,
      ff1, nullptr, N_NODES, 2 * C_DIM, C_DIM);
  gemm_bt<1><<<dim3(64, 8), 256, 0, stream>>>(ff1, wbF2, ffn_b2, ff2,
      N_NODES, C_DIM, 2 * C_DIM, nullptr);
  ln2_kernel<<<N_NODES / 4, 256, 0, stream>>>(hidden_f, ff2, n2g, n2b, out);
}

// Round 12
// 272.121 us; speedup vs baseline: 1.1081x; 1.0344x over previous
//
#include <hip/hip_runtime.h>

// SGFormer encoder layer, MI355X gfx950.
// fp32 I/O per reference dtypes; bf16 MFMA internally.
// R2: CSR+gather scatter-mean. R3/4: static-max flash attn, V^T, K-split.
// R5: SPLITS=4, merged LQKV gemm. R7: f2b_up P. R8: glls+XOR-swizzle staging.
// R11: bf16 split-partials, VALU lsum (attn pinned at VGPR 64 / 32% occ).
// R12: gemm_bt BK=128 (halves barrier drains; LDS 32KB, grid-limited anyway);
//      ffn1 moved from gemm128 (256 blocks = 1/CU!) to 64^2 gemm_bt + fused
//      GELU (1024 blocks = 4/CU).

#define N_NODES 4096
#define C_DIM   512
#define H_HEADS 8
#define D_HEAD  64
#define E_EDGES 131072

typedef unsigned short u16;
typedef unsigned int   u32;
typedef u16   u16x8  __attribute__((ext_vector_type(8)));
typedef __bf16 bf16x8 __attribute__((ext_vector_type(8)));
typedef float  f32x4  __attribute__((ext_vector_type(4)));

__device__ __forceinline__ float b2f(u16 u) {
  unsigned int i = ((unsigned int)u) << 16;
  return __builtin_bit_cast(float, i);
}
__device__ __forceinline__ u16 f2b(float f) {
  unsigned int i = __builtin_bit_cast(unsigned int, f);
  i += 0x7fffu + ((i >> 16) & 1u);   // RNE
  return (u16)(i >> 16);
}
__device__ __forceinline__ u16 f2b_up(float f) {   // round-half-up (cheaper)
  unsigned int i = __builtin_bit_cast(unsigned int, f);
  return (u16)((i + 0x8000u) >> 16);
}
// async global->LDS, 16B per lane; LDS dest = wave-uniform base + lane*16
__device__ __forceinline__ void glds16(const u16* g, u16* l) {
  __builtin_amdgcn_global_load_lds(
      (const __attribute__((address_space(1))) void*)g,
      (__attribute__((address_space(3))) void*)l, 16, 0, 0);
}

// ---------------- fp32 -> bf16 batched convert (+ fused hist) ----------------
struct CvtArgs {
  const float* src[7];
  u16* dst[7];
  int n[7];
  const int* ei;
  int* deg;
};

__global__ __launch_bounds__(256) void cvt_multi(CvtArgs a) {
  const int t = blockIdx.y;
  if (t == 7) {                       // fused degree histogram
    if (blockIdx.x >= E_EDGES / 256) return;
    const int e = blockIdx.x * 256 + threadIdx.x;
    atomicAdd(&a.deg[a.ei[E_EDGES + e]], 1);
    return;
  }
  const int i = (blockIdx.x * 256 + threadIdx.x) * 8;
  if (i >= a.n[t]) return;
  const float* s = a.src[t] + i;
  f32x4 v0 = *(const f32x4*)s;
  f32x4 v1 = *(const f32x4*)(s + 4);
  u16x8 o;
  o[0]=f2b(v0[0]); o[1]=f2b(v0[1]); o[2]=f2b(v0[2]); o[3]=f2b(v0[3]);
  o[4]=f2b(v1[0]); o[5]=f2b(v1[1]); o[6]=f2b(v1[2]); o[7]=f2b(v1[3]);
  *(u16x8*)(a.dst[t] + i) = o;
}

// ---------------- 64x64 tile GEMM, BK=128: out = A * W^T + bias -------------
// EPI: 1 = f32 out, 2 = gelu -> bf16, 3 = 0.5*local+0.5*v -> bf16
// glls staging, XOR-swizzled LDS (slot g holds granule g ^ (row&7)).
template<int EPI>
__global__ __launch_bounds__(256) void gemm_bt(
    const u16* __restrict__ A, const u16* __restrict__ W,
    const float* __restrict__ bias, void* __restrict__ outp,
    int M, int Nout, int K,
    const float* __restrict__ mloc)
{
  const int tid  = threadIdx.x;
  const int lane = tid & 63, wave = tid >> 6;
  const int quad = lane >> 4, l16 = lane & 15;
  const int wm = wave >> 1, wn = wave & 1;   // 2x2 wave grid, 32x32 per wave
  const int bm = blockIdx.x, bnb = blockIdx.y;

  __shared__ __align__(16) u16 As[64][128];   // BK=128, 32KB total
  __shared__ __align__(16) u16 Ws[64][128];

  f32x4 acc[2][2] = {};

  // staging: one glls16 covers 4 rows (128-u16 rows); lane -> row lr4, gran gs
  const int lr4 = lane >> 4, gs = lane & 15;
  const int g8e = (gs ^ lr4) * 8;         // c even: row&7 == lr4
  const int g8o = (gs ^ (4 + lr4)) * 8;   // c odd:  row&7 == 4+lr4
  const u16* aw[8];
#pragma unroll
  for (int c = 0; c < 4; ++c) {
    const int g8 = (c & 1) ? g8o : g8e;
    aw[c]     = A + (size_t)(bm  * 64 + wave * 16 + c * 4 + lr4) * K + g8;
    aw[4 + c] = W + (size_t)(bnb * 64 + wave * 16 + c * 4 + lr4) * K + g8;
  }

  for (int k0 = 0; k0 < K; k0 += 128) {
    __syncthreads();                  // prior iter's LDS reads complete
#pragma unroll
    for (int c = 0; c < 4; ++c) {
      glds16(aw[c] + k0,     &As[wave * 16 + c * 4][0]);
      glds16(aw[4 + c] + k0, &Ws[wave * 16 + c * 4][0]);
    }
    __syncthreads();                  // drains vmcnt (glls) before reads
#pragma unroll
    for (int ks = 0; ks < 4; ++ks) {
      const int slot = ((ks * 4 + quad) ^ (l16 & 7)) * 8;
      bf16x8 af[2], bf[2];
      af[0] = *(const bf16x8*)&As[wm * 32 +      l16][slot];
      af[1] = *(const bf16x8*)&As[wm * 32 + 16 + l16][slot];
      bf[0] = *(const bf16x8*)&Ws[wn * 32 +      l16][slot];
      bf[1] = *(const bf16x8*)&Ws[wn * 32 + 16 + l16][slot];
#pragma unroll
      for (int i = 0; i < 2; ++i)
#pragma unroll
        for (int j = 0; j < 2; ++j)
          acc[i][j] = __builtin_amdgcn_mfma_f32_16x16x32_bf16(af[i], bf[j], acc[i][j], 0, 0, 0);
    }
  }

#pragma unroll
  for (int i = 0; i < 2; ++i)
#pragma unroll
    for (int j = 0; j < 2; ++j) {
      const int col = bnb * 64 + wn * 32 + j * 16 + l16;
      const float bias_v = bias[col];
#pragma unroll
      for (int r = 0; r < 4; ++r) {
        const int row = bm * 64 + wm * 32 + i * 16 + quad * 4 + r;
        float v = acc[i][j][r] + bias_v;
        const size_t o = (size_t)row * Nout + col;
        if constexpr (EPI == 1) {
          ((float*)outp)[o] = v;
        } else if constexpr (EPI == 2) {
          float gl = 0.5f * v * (1.0f + erff(v * 0.70710678118654752f));
          ((u16*)outp)[o] = f2b(gl);
        } else {
          ((u16*)outp)[o] = f2b(0.5f * mloc[o] + 0.5f * v);
        }
      }
    }
}

// ---------------- 128x128 tile GEMM (glls staging, BK=64) -------------------
// MODE 0: split LQKV epilogue (col<512 -> local_h, else qkvb w/ bias1)
__global__ __launch_bounds__(256) void gemm128(
    const u16* __restrict__ A, const u16* __restrict__ W,
    const float* __restrict__ bias0, const float* __restrict__ bias1,
    u16* __restrict__ out0, u16* __restrict__ out1,
    int M, int Nout, int K)
{
  const int tid  = threadIdx.x;
  const int lane = tid & 63, wave = tid >> 6;
  const int quad = lane >> 4, l16 = lane & 15;
  const int wm = wave >> 1, wn = wave & 1;   // 2x2 wave grid, 64x64 per wave
  const int bm = blockIdx.x, bnb = blockIdx.y;

  __shared__ __align__(16) u16 As[128][64];
  __shared__ __align__(16) u16 Ws[128][64];

  f32x4 acc[4][4] = {};

  const int lr = lane >> 3, gs = lane & 7;
  const int g8 = (gs ^ lr) * 8;
  const u16* ab = A + (size_t)(bm  * 128 + wave * 32 + lr) * K + g8;
  const u16* wb = W + (size_t)(bnb * 128 + wave * 32 + lr) * K + g8;

  for (int k0 = 0; k0 < K; k0 += 64) {
    __syncthreads();
#pragma unroll
    for (int c = 0; c < 4; ++c) {
      glds16(ab + (size_t)(c * 8) * K + k0, &As[wave * 32 + c * 8][0]);
      glds16(wb + (size_t)(c * 8) * K + k0, &Ws[wave * 32 + c * 8][0]);
    }
    __syncthreads();
#pragma unroll
    for (int ks = 0; ks < 2; ++ks) {
      const int slot = ((ks * 4 + quad) ^ (l16 & 7)) * 8;
      bf16x8 af[4], bf[4];
#pragma unroll
      for (int am = 0; am < 4; ++am)
        af[am] = *(const bf16x8*)&As[wm * 64 + am * 16 + l16][slot];
#pragma unroll
      for (int bn = 0; bn < 4; ++bn)
        bf[bn] = *(const bf16x8*)&Ws[wn * 64 + bn * 16 + l16][slot];
#pragma unroll
      for (int am = 0; am < 4; ++am)
#pragma unroll
        for (int bn = 0; bn < 4; ++bn)
          acc[am][bn] = __builtin_amdgcn_mfma_f32_16x16x32_bf16(af[am], bf[bn], acc[am][bn], 0, 0, 0);
    }
  }

#pragma unroll
  for (int am = 0; am < 4; ++am)
#pragma unroll
    for (int bn = 0; bn < 4; ++bn) {
      const int col = bnb * 128 + wn * 64 + bn * 16 + l16;
      const float bias_v = (col < 512) ? bias0[col] : bias1[col - 512];
#pragma unroll
      for (int r = 0; r < 4; ++r) {
        const int row = bm * 128 + wm * 64 + am * 16 + quad * 4 + r;
        float v = acc[am][bn][r] + bias_v;
        if (col < 512) out0[(size_t)row * 512 + col] = f2b(v);
        else           out1[(size_t)row * 1536 + (col - 512)] = f2b(v);
      }
    }
}

// ---------------- CSR build (by destination) ----------------
__global__ __launch_bounds__(256) void scan_kernel(
    const int* __restrict__ deg, int* __restrict__ off, int* __restrict__ cursor)
{
  __shared__ int part[256];
  const int t = threadIdx.x;
  int v[16];
  int s = 0;
#pragma unroll
  for (int i = 0; i < 16; ++i) { v[i] = deg[t * 16 + i]; s += v[i]; }
  part[t] = s;
  __syncthreads();
  for (int d = 1; d < 256; d <<= 1) {
    int val = (t >= d) ? part[t - d] : 0;
    __syncthreads();
    if (t >= d) part[t] += val;
    __syncthreads();
  }
  int prefix = (t == 0) ? 0 : part[t - 1];
#pragma unroll
  for (int i = 0; i < 16; ++i) {
    off[t * 16 + i] = prefix;
    cursor[t * 16 + i] = prefix;
    prefix += v[i];
  }
  if (t == 255) off[4096] = prefix;
}

__global__ __launch_bounds__(256) void fill_kernel(
    const int* __restrict__ ei, int* __restrict__ cursor, int* __restrict__ csr)
{
  const int e = blockIdx.x * 256 + threadIdx.x;
  const int s = ei[e];
  const int d = ei[E_EDGES + e];
  const int p = atomicAdd(&cursor[d], 1);
  csr[p] = s;
}

// ---------------- fused gather-mean (fp32 local_out) + V transpose ----------
__global__ __launch_bounds__(256) void gather_vtrans(
    const int* __restrict__ off, const int* __restrict__ csr,
    const u16* __restrict__ lh, float* __restrict__ lo,
    const u16* __restrict__ qkv, u16* __restrict__ vt)
{
  if (blockIdx.y == 0) {              // gather: one wave per dst node
    const int wave = threadIdx.x >> 6, lane = threadIdx.x & 63;
    const int n = blockIdx.x * 4 + wave;
    const int j0 = off[n], j1 = off[n + 1];
    float acc[8] = {};
    for (int j = j0; j < j1; ++j) {
      const int s = csr[j];
      const u16x8 v = *(const u16x8*)(lh + (size_t)s * C_DIM + lane * 8);
#pragma unroll
      for (int i = 0; i < 8; ++i) acc[i] += b2f(v[i]);
    }
    const float inv = 1.0f / fmaxf((float)(j1 - j0), 1.0f);
    f32x4 o0, o1;
#pragma unroll
    for (int i = 0; i < 4; ++i) { o0[i] = acc[i] * inv; o1[i] = acc[4 + i] * inv; }
    float* op = lo + (size_t)n * C_DIM + lane * 8;
    *(f32x4*)op = o0;
    *(f32x4*)(op + 4) = o1;
  } else {                            // vtrans: vt[h][d][m] = V[m][h][d]
    if (blockIdx.x >= 512) return;
    const int tid = threadIdx.x;
    const int d = tid & 63, mg = tid >> 6;
    const int h = blockIdx.x >> 6, mt = blockIdx.x & 63;
    const int m0 = mt * 64 + mg * 16;
    u16 buf[16];
#pragma unroll
    for (int i = 0; i < 16; ++i)
      buf[i] = qkv[(size_t)(m0 + i) * 1536 + 1024 + h * 64 + d];
    u16x8 w0, w1;
#pragma unroll
    for (int i = 0; i < 8; ++i) { w0[i] = buf[i]; w1[i] = buf[8 + i]; }
    u16* op = vt + (size_t)(h * 64 + d) * N_NODES + m0;
    *(u16x8*)op = w0;
    *(u16x8*)(op + 8) = w1;
  }
}

// ---------------- flash attention (static max, K-split, glls staging) -------
// VALU lsum + 16-lane shuffle (VGPR 64 loop); bf16 split partials.
template<int SPLITS>
__global__ __launch_bounds__(256) void attn_kernel(
    const u16* __restrict__ qkv, const u16* __restrict__ vt,
    u16* __restrict__ opart, float* __restrict__ lpart)
{
  const int tid = threadIdx.x, wave = tid >> 6, lane = tid & 63;
  const int quad = lane >> 4, l16 = lane & 15;
  const int h = blockIdx.y, tile = blockIdx.x, split = blockIdx.z;

  __shared__ __align__(16) u16 Ks[64][64];    // K tile, XOR-swizzled
  __shared__ __align__(16) u16 Vts[64][64];   // V^T tile, XOR-swizzled
  __shared__ __align__(16) u16 Ps[128][72];   // P [row][m'] (padded, VALU-written)

  const float QSCALE = 0.18033688011112042f;  // log2(e)/8
  bf16x8 aq[2][2];
#pragma unroll
  for (int mb = 0; mb < 2; ++mb) {
    const int qrow = tile * 128 + wave * 32 + mb * 16 + l16;
    const u16* qp = qkv + (size_t)qrow * 1536 + h * 64 + quad * 8;
    u16x8 q0 = *(const u16x8*)qp;
    u16x8 q1 = *(const u16x8*)(qp + 32);
    u16x8 s0, s1;
#pragma unroll
    for (int i = 0; i < 8; ++i) {
      s0[i] = f2b(b2f(q0[i]) * QSCALE);
      s1[i] = f2b(b2f(q1[i]) * QSCALE);
    }
    aq[mb][0] = __builtin_bit_cast(bf16x8, s0);
    aq[mb][1] = __builtin_bit_cast(bf16x8, s1);
  }

  f32x4 O[2][4] = {};
  float lsum[2][4] = {};   // per-lane partial row sums

  const int lr = lane >> 3, gs = lane & 7;
  const int g8 = (gs ^ lr) * 8;
  const int R0 = wave * 16 + lr;

  const int mt1 = (split + 1) * (64 / SPLITS);
  for (int mt = split * (64 / SPLITS); mt < mt1; ++mt) {
    __syncthreads();
    glds16(qkv + (size_t)(mt * 64 + R0)     * 1536 + 512 + h * 64 + g8, &Ks[wave * 16][0]);
    glds16(qkv + (size_t)(mt * 64 + R0 + 8) * 1536 + 512 + h * 64 + g8, &Ks[wave * 16 + 8][0]);
    glds16(vt + (size_t)(h * 64 + R0)     * N_NODES + mt * 64 + g8, &Vts[wave * 16][0]);
    glds16(vt + (size_t)(h * 64 + R0 + 8) * N_NODES + mt * 64 + g8, &Vts[wave * 16 + 8][0]);
    __syncthreads();

    // S = (cQ) K^T
    f32x4 s[2][4] = {};
#pragma unroll
    for (int ks = 0; ks < 2; ++ks) {
      const int slot = ((ks * 4 + quad) ^ (l16 & 7)) * 8;
      bf16x8 bk[4];
#pragma unroll
      for (int jn = 0; jn < 4; ++jn)
        bk[jn] = *(const bf16x8*)&Ks[jn * 16 + l16][slot];
#pragma unroll
      for (int mb = 0; mb < 2; ++mb)
#pragma unroll
        for (int jn = 0; jn < 4; ++jn)
          s[mb][jn] = __builtin_amdgcn_mfma_f32_16x16x32_bf16(aq[mb][ks], bk[jn], s[mb][jn], 0, 0, 0);
    }

    // p = exp2(s); accumulate per-lane partial sums; half-up bf16 store
#pragma unroll
    for (int mb = 0; mb < 2; ++mb)
#pragma unroll
      for (int jn = 0; jn < 4; ++jn)
#pragma unroll
        for (int r = 0; r < 4; ++r) {
          float p = __builtin_amdgcn_exp2f(s[mb][jn][r]);
          lsum[mb][r] += p;
          Ps[wave * 32 + mb * 16 + quad * 4 + r][jn * 16 + l16] = f2b_up(p);
        }
    // no barrier: Ps rows are wave-private; lgkmcnt ordering handles RAW

    // O += P V
#pragma unroll
    for (int ks = 0; ks < 2; ++ks) {
      const int slot = ((ks * 4 + quad) ^ (l16 & 7)) * 8;
      bf16x8 bv[4];
#pragma unroll
      for (int jd = 0; jd < 4; ++jd)
        bv[jd] = *(const bf16x8*)&Vts[jd * 16 + l16][slot];
#pragma unroll
      for (int mb = 0; mb < 2; ++mb) {
        bf16x8 ap = *(const bf16x8*)&Ps[wave * 32 + mb * 16 + l16][ks * 32 + quad * 8];
#pragma unroll
        for (int jd = 0; jd < 4; ++jd)
          O[mb][jd] = __builtin_amdgcn_mfma_f32_16x16x32_bf16(ap, bv[jd], O[mb][jd], 0, 0, 0);
      }
    }
  }

  // one-time 16-lane reduce of row-sum partials
#pragma unroll
  for (int mb = 0; mb < 2; ++mb)
#pragma unroll
    for (int r = 0; r < 4; ++r)
#pragma unroll
      for (int off = 1; off < 16; off <<= 1)
        lsum[mb][r] += __shfl_xor(lsum[mb][r], off);

  // write unnormalized partials (bf16) + row sums
#pragma unroll
  for (int mb = 0; mb < 2; ++mb)
#pragma unroll
    for (int r = 0; r < 4; ++r) {
      const int row = tile * 128 + wave * 32 + mb * 16 + quad * 4 + r;
      u16* orow = opart + ((size_t)split * N_NODES + row) * C_DIM + h * 64;
#pragma unroll
      for (int jd = 0; jd < 4; ++jd)
        orow[jd * 16 + l16] = f2b(O[mb][jd][r]);
      if (l16 == 0)
        lpart[((size_t)split * N_NODES + row) * H_HEADS + h] = lsum[mb][r];
    }
}

template<int SPLITS>
__global__ __launch_bounds__(256) void attn_combine(
    const u16* __restrict__ opart, const float* __restrict__ lpart,
    u16* __restrict__ ctx)
{
  const size_t base = (size_t)(blockIdx.x * 256 + threadIdx.x) * 8;
  const int row = (int)(base >> 9);
  const int h = (int)((base & 511) >> 6);
  float l = 0.0f;
#pragma unroll
  for (int s = 0; s < SPLITS; ++s)
    l += lpart[(size_t)s * N_NODES * H_HEADS + (size_t)row * H_HEADS + h];
  const float inv = 1.0f / l;
  float o[8] = {};
#pragma unroll
  for (int s = 0; s < SPLITS; ++s) {
    const u16x8 p = *(const u16x8*)(opart + (size_t)s * N_NODES * C_DIM + base);
#pragma unroll
    for (int i = 0; i < 8; ++i) o[i] += b2f(p[i]);
  }
  u16x8 ob;
#pragma unroll
  for (int i = 0; i < 8; ++i) ob[i] = f2b(o[i] * inv);
  *(u16x8*)(ctx + base) = ob;
}

// ---------------- LayerNorms (one wave per row) ----------------
__global__ __launch_bounds__(256) void ln1_kernel(
    const float* __restrict__ x, const float* __restrict__ pr,
    const float* __restrict__ g, const float* __restrict__ b,
    u16* __restrict__ hb, float* __restrict__ hf)
{
  const int wave = threadIdx.x >> 6, lane = threadIdx.x & 63;
  const int row = blockIdx.x * 4 + wave;
  const int c0 = lane * 8;
  const size_t base = (size_t)row * C_DIM + c0;
  f32x4 x0 = *(const f32x4*)(x + base);
  f32x4 x1 = *(const f32x4*)(x + base + 4);
  f32x4 p0 = *(const f32x4*)(pr + base);
  f32x4 p1 = *(const f32x4*)(pr + base + 4);
  float v[8];
#pragma unroll
  for (int i = 0; i < 4; ++i) { v[i] = x0[i] + p0[i]; v[4 + i] = x1[i] + p1[i]; }
  float sum = 0, sq = 0;
#pragma unroll
  for (int i = 0; i < 8; ++i) { sum += v[i]; sq += v[i] * v[i]; }
  for (int off = 1; off < 64; off <<= 1) { sum += __shfl_xor(sum, off); sq += __shfl_xor(sq, off); }
  const float mean = sum * (1.0f / C_DIM);
  const float var  = sq * (1.0f / C_DIM) - mean * mean;
  const float rstd = rsqrtf(var + 1e-5f);
  f32x4 g0 = *(const f32x4*)(g + c0), g1 = *(const f32x4*)(g + c0 + 4);
  f32x4 b0 = *(const f32x4*)(b + c0), b1 = *(const f32x4*)(b + c0 + 4);
  u16x8 ob; f32x4 h0, h1;
#pragma unroll
  for (int i = 0; i < 4; ++i) {
    float hv0 = (v[i]     - mean) * rstd * g0[i] + b0[i];
    float hv1 = (v[4 + i] - mean) * rstd * g1[i] + b1[i];
    h0[i] = hv0; h1[i] = hv1;
    ob[i] = f2b(hv0); ob[4 + i] = f2b(hv1);
  }
  *(u16x8*)(hb + base) = ob;
  *(f32x4*)(hf + base) = h0;
  *(f32x4*)(hf + base + 4) = h1;
}

__global__ __launch_bounds__(256) void ln2_kernel(
    const float* __restrict__ a, const float* __restrict__ c,
    const float* __restrict__ g, const float* __restrict__ b,
    float* __restrict__ out)
{
  const int wave = threadIdx.x >> 6, lane = threadIdx.x & 63;
  const int row = blockIdx.x * 4 + wave;
  const int c0 = lane * 8;
  const size_t base = (size_t)row * C_DIM + c0;
  f32x4 a0 = *(const f32x4*)(a + base), a1 = *(const f32x4*)(a + base + 4);
  f32x4 c0v = *(const f32x4*)(c + base), c1v = *(const f32x4*)(c + base + 4);
  float v[8];
#pragma unroll
  for (int i = 0; i < 4; ++i) { v[i] = a0[i] + c0v[i]; v[4 + i] = a1[i] + c1v[i]; }
  float sum = 0, sq = 0;
#pragma unroll
  for (int i = 0; i < 8; ++i) { sum += v[i]; sq += v[i] * v[i]; }
  for (int off = 1; off < 64; off <<= 1) { sum += __shfl_xor(sum, off); sq += __shfl_xor(sq, off); }
  const float mean = sum * (1.0f / C_DIM);
  const float var  = sq * (1.0f / C_DIM) - mean * mean;
  const float rstd = rsqrtf(var + 1e-5f);
  f32x4 g0 = *(const f32x4*)(g + c0), g1 = *(const f32x4*)(g + c0 + 4);
  f32x4 b0 = *(const f32x4*)(b + c0), b1 = *(const f32x4*)(b + c0 + 4);
  f32x4 h0, h1;
#pragma unroll
  for (int i = 0; i < 4; ++i) {
    h0[i] = (v[i]     - mean) * rstd * g0[i] + b0[i];
    h1[i] = (v[4 + i] - mean) * rstd * g1[i] + b1[i];
  }
  *(f32x4*)(out + base) = h0;
  *(f32x4*)(out + base + 4) = h1;
}

// ---------------- launch ----------------
extern "C" void kernel_launch(void* const* d_in, const int* in_sizes, int n_in,
                              void* d_out, int out_size, void* d_ws, size_t ws_size,
                              hipStream_t stream) {
  const float* x          = (const float*)d_in[0];
  const int*   ei         = (const int*)d_in[1];
  const float* local_w    = (const float*)d_in[2];
  const float* local_b    = (const float*)d_in[3];
  const float* in_proj_w  = (const float*)d_in[4];
  const float* in_proj_b  = (const float*)d_in[5];
  const float* attn_out_w = (const float*)d_in[6];
  const float* attn_out_b = (const float*)d_in[7];
  const float* output_w   = (const float*)d_in[8];
  const float* output_b   = (const float*)d_in[9];
  const float* n1g = (const float*)d_in[10];
  const float* n1b = (const float*)d_in[11];
  const float* n2g = (const float*)d_in[12];
  const float* n2b = (const float*)d_in[13];
  const float* ffn_w1 = (const float*)d_in[14];
  const float* ffn_b1 = (const float*)d_in[15];
  const float* ffn_w2 = (const float*)d_in[16];
  const float* ffn_b2 = (const float*)d_in[17];
  float* out = (float*)d_out;

  char* ws = (char*)d_ws;
  size_t o = 0;
  float* local_out = (float*)(ws + o); o += (size_t)N_NODES * C_DIM * 4;  // 8 MB
  int* deg    = (int*)(ws + o); o += (N_NODES) * 4;
  int* off    = (int*)(ws + o); o += (N_NODES + 16) * 4;
  int* cursor = (int*)(ws + o); o += (N_NODES) * 4;
  int* csr    = (int*)(ws + o); o += (size_t)E_EDGES * 4;
  u16* xb   = (u16*)(ws + o); o += (size_t)N_NODES * C_DIM * 2;           // 4 MB
  u16* wbLQ = (u16*)(ws + o); o += (size_t)4 * C_DIM * C_DIM * 2;         // 2 MB
  u16* wbA  = (u16*)(ws + o); o += (size_t)C_DIM * C_DIM * 2;
  u16* wbO  = (u16*)(ws + o); o += (size_t)C_DIM * C_DIM * 2;
  u16* wbF1 = (u16*)(ws + o); o += (size_t)2 * C_DIM * C_DIM * 2;
  u16* wbF2 = (u16*)(ws + o); o += (size_t)2 * C_DIM * C_DIM * 2;
  u16* local_h   = (u16*)(ws + o); o += (size_t)N_NODES * C_DIM * 2;
  u16* qkvb      = (u16*)(ws + o); o += (size_t)N_NODES * 3 * C_DIM * 2;  // 12 MB
  u16* ctxb      = (u16*)(ws + o); o += (size_t)N_NODES * C_DIM * 2;
  u16* mixed     = (u16*)(ws + o); o += (size_t)N_NODES * C_DIM * 2;
  u16* hidden_bf = (u16*)(ws + o); o += (size_t)N_NODES * C_DIM * 2;      // 4 MB
  float* hidden_f = (float*)(ws + o); o += (size_t)N_NODES * C_DIM * 4;   // 8 MB
  u16* ff1       = (u16*)(ws + o); o += (size_t)N_NODES * 2 * C_DIM * 2;  // 8 MB
  // aliases (dead ranges reused):
  float* proj  = (float*)qkvb;       // qkv dead after attn; proj 8 MB <= 12 MB
  float* ff2   = (float*)local_out;  // local_out dead after mix-epilogue gemm
  u16*   vt    = xb;                 // xb dead after LQKV gemm; 4 MB
  // SPLITS=4 bf16 partials (16.25 MB) past static region if workspace allows
  u16* opart4 = (u16*)(ws + o);
  float* lpart4 = (float*)(ws + o + (size_t)4 * N_NODES * C_DIM * 2);
  const size_t need4 = o + (size_t)4 * N_NODES * C_DIM * 2 + (size_t)4 * N_NODES * H_HEADS * 4;
  const bool use4 = (ws_size >= need4);
  // SPLITS=2 fallback: inside hidden_bf..ff1 region (8.25 MB <= 20 MB)
  u16* opart2 = (u16*)hidden_bf;
  float* lpart2 = (float*)(opart2 + (size_t)2 * N_NODES * C_DIM);

  (void)hipMemsetAsync(deg, 0, N_NODES * 4, stream);

  // fp32 -> bf16 conversions (x + weights) + fused degree histogram
  CvtArgs ca;
  ca.src[0] = x;          ca.dst[0] = xb;   ca.n[0] = N_NODES * C_DIM;
  ca.src[1] = local_w;    ca.dst[1] = wbLQ;                  ca.n[1] = C_DIM * C_DIM;
  ca.src[2] = in_proj_w;  ca.dst[2] = wbLQ + C_DIM * C_DIM;  ca.n[2] = 3 * C_DIM * C_DIM;
  ca.src[3] = attn_out_w; ca.dst[3] = wbA;  ca.n[3] = C_DIM * C_DIM;
  ca.src[4] = output_w;   ca.dst[4] = wbO;  ca.n[4] = C_DIM * C_DIM;
  ca.src[5] = ffn_w1;     ca.dst[5] = wbF1; ca.n[5] = 2 * C_DIM * C_DIM;
  ca.src[6] = ffn_w2;     ca.dst[6] = wbF2; ca.n[6] = 2 * C_DIM * C_DIM;
  ca.ei = ei; ca.deg = deg;
  cvt_multi<<<dim3(N_NODES * C_DIM / 2048, 8), 256, 0, stream>>>(ca);

  // CSR build
  scan_kernel<<<1, 256, 0, stream>>>(deg, off, cursor);
  fill_kernel<<<E_EDGES / 256, 256, 0, stream>>>(ei, cursor, csr);

  // merged local+qkv GEMM: [local_h | qkvb] = xb @ [local_w; in_proj_w]^T
  gemm128<<<dim3(32, 16), 256, 0, stream>>>(xb, wbLQ, local_b, in_proj_b,
      local_h, qkvb, N_NODES, 4 * C_DIM, C_DIM);

  // gather-mean + V transpose (fused; xb dead after LQKV gemm)
  gather_vtrans<<<dim3(N_NODES / 4, 2), 256, 0, stream>>>(off, csr, local_h,
      local_out, qkvb, vt);

  // attention
  if (use4) {
    attn_kernel<4><<<dim3(32, 8, 4), 256, 0, stream>>>(qkvb, vt, opart4, lpart4);
    attn_combine<4><<<N_NODES * C_DIM / 2048, 256, 0, stream>>>(opart4, lpart4, ctxb);
  } else {
    attn_kernel<2><<<dim3(32, 8, 2), 256, 0, stream>>>(qkvb, vt, opart2, lpart2);
    attn_combine<2><<<N_NODES * C_DIM / 2048, 256, 0, stream>>>(opart2, lpart2, ctxb);
  }

  // mixed = 0.5*local_out + 0.5*(ctx @ attn_out_w^T + b)
  gemm_bt<3><<<dim3(64, 8), 256, 0, stream>>>(ctxb, wbA, attn_out_b, mixed,
      N_NODES, C_DIM, C_DIM, local_out);

  // proj = mixed @ output_w^T + b ; hidden = LN(x + proj)
  gemm_bt<1><<<dim3(64, 8), 256, 0, stream>>>(mixed, wbO, output_b, proj,
      N_NODES, C_DIM, C_DIM, nullptr);
  ln1_kernel<<<N_NODES / 4, 256, 0, stream>>>(x, proj, n1g, n1b, hidden_bf, hidden_f);

  // FFN (ffn1 on 64^2 tile + fused GELU: 1024 blocks = 4/CU, was 256 = 1/CU)
  gemm_bt<2><<<dim3(64, 16), 256, 0, stream>>>(hidden_bf, wbF1, ffn_b1, ff1,
      N_NODES, 2 * C_DIM, C_DIM, nullptr);
  gemm_bt<1><<<dim3(64, 8), 256, 0, stream>>>(ff1, wbF2, ffn_b2, ff2,
      N_NODES, C_DIM, 2 * C_DIM, nullptr);
  ln2_kernel<<<N_NODES / 4, 256, 0, stream>>>(hidden_f, ff2, n2g, n2b, out);
}

// Round 13
// 264.193 us; speedup vs baseline: 1.1414x; 1.0300x over previous
//
#include <hip/hip_runtime.h>

// SGFormer encoder layer, MI355X gfx950.
// fp32 I/O per reference dtypes; bf16 MFMA internally.
// R2: CSR+gather scatter-mean. R3/4: static-max flash attn, V^T, K-split.
// R5: SPLITS=4, merged LQKV gemm. R7: f2b_up P. R8: glls+XOR-swizzle staging.
// R11: bf16 split-partials, VALU lsum. R12: gemm_bt BK=128; ffn1 on 64^2 tile.
// R13: dispatch compaction (13 -> 11): deg-zero in cvt slice; hist in LQKV
//      dispatch; scan+vtrans merged; fill rides attn (z==SPLITS slice);
//      gather+combine merged. Small kernels hide under big dispatches.

#define N_NODES 4096
#define C_DIM   512
#define H_HEADS 8
#define D_HEAD  64
#define E_EDGES 131072

typedef unsigned short u16;
typedef unsigned int   u32;
typedef u16   u16x8  __attribute__((ext_vector_type(8)));
typedef __bf16 bf16x8 __attribute__((ext_vector_type(8)));
typedef float  f32x4  __attribute__((ext_vector_type(4)));

__device__ __forceinline__ float b2f(u16 u) {
  unsigned int i = ((unsigned int)u) << 16;
  return __builtin_bit_cast(float, i);
}
__device__ __forceinline__ u16 f2b(float f) {
  unsigned int i = __builtin_bit_cast(unsigned int, f);
  i += 0x7fffu + ((i >> 16) & 1u);   // RNE
  return (u16)(i >> 16);
}
__device__ __forceinline__ u16 f2b_up(float f) {   // round-half-up (cheaper)
  unsigned int i = __builtin_bit_cast(unsigned int, f);
  return (u16)((i + 0x8000u) >> 16);
}
// async global->LDS, 16B per lane; LDS dest = wave-uniform base + lane*16
__device__ __forceinline__ void glds16(const u16* g, u16* l) {
  __builtin_amdgcn_global_load_lds(
      (const __attribute__((address_space(1))) void*)g,
      (__attribute__((address_space(3))) void*)l, 16, 0, 0);
}

// ---------------- fp32 -> bf16 batched convert (+ deg zero slice) ----------
struct CvtArgs {
  const float* src[7];
  u16* dst[7];
  int n[7];
  int* deg;
};

__global__ __launch_bounds__(256) void cvt_multi(CvtArgs a) {
  const int t = blockIdx.y;
  if (t == 7) {                       // zero degree counters (ws is poisoned)
    const int i = blockIdx.x * 256 + threadIdx.x;
    if (i < N_NODES) a.deg[i] = 0;
    return;
  }
  const int i = (blockIdx.x * 256 + threadIdx.x) * 8;
  if (i >= a.n[t]) return;
  const float* s = a.src[t] + i;
  f32x4 v0 = *(const f32x4*)s;
  f32x4 v1 = *(const f32x4*)(s + 4);
  u16x8 o;
  o[0]=f2b(v0[0]); o[1]=f2b(v0[1]); o[2]=f2b(v0[2]); o[3]=f2b(v0[3]);
  o[4]=f2b(v1[0]); o[5]=f2b(v1[1]); o[6]=f2b(v1[2]); o[7]=f2b(v1[3]);
  *(u16x8*)(a.dst[t] + i) = o;
}

// ---------------- 64x64 tile GEMM, BK=128: out = A * W^T + bias -------------
// EPI: 1 = f32 out, 2 = gelu -> bf16, 3 = 0.5*local+0.5*v -> bf16
template<int EPI>
__global__ __launch_bounds__(256) void gemm_bt(
    const u16* __restrict__ A, const u16* __restrict__ W,
    const float* __restrict__ bias, void* __restrict__ outp,
    int M, int Nout, int K,
    const float* __restrict__ mloc)
{
  const int tid  = threadIdx.x;
  const int lane = tid & 63, wave = tid >> 6;
  const int quad = lane >> 4, l16 = lane & 15;
  const int wm = wave >> 1, wn = wave & 1;   // 2x2 wave grid, 32x32 per wave
  const int bm = blockIdx.x, bnb = blockIdx.y;

  __shared__ __align__(16) u16 As[64][128];   // BK=128, 32KB total
  __shared__ __align__(16) u16 Ws[64][128];

  f32x4 acc[2][2] = {};

  const int lr4 = lane >> 4, gs = lane & 15;
  const int g8e = (gs ^ lr4) * 8;         // c even: row&7 == lr4
  const int g8o = (gs ^ (4 + lr4)) * 8;   // c odd:  row&7 == 4+lr4
  const u16* aw[8];
#pragma unroll
  for (int c = 0; c < 4; ++c) {
    const int g8 = (c & 1) ? g8o : g8e;
    aw[c]     = A + (size_t)(bm  * 64 + wave * 16 + c * 4 + lr4) * K + g8;
    aw[4 + c] = W + (size_t)(bnb * 64 + wave * 16 + c * 4 + lr4) * K + g8;
  }

  for (int k0 = 0; k0 < K; k0 += 128) {
    __syncthreads();
#pragma unroll
    for (int c = 0; c < 4; ++c) {
      glds16(aw[c] + k0,     &As[wave * 16 + c * 4][0]);
      glds16(aw[4 + c] + k0, &Ws[wave * 16 + c * 4][0]);
    }
    __syncthreads();
#pragma unroll
    for (int ks = 0; ks < 4; ++ks) {
      const int slot = ((ks * 4 + quad) ^ (l16 & 7)) * 8;
      bf16x8 af[2], bf[2];
      af[0] = *(const bf16x8*)&As[wm * 32 +      l16][slot];
      af[1] = *(const bf16x8*)&As[wm * 32 + 16 + l16][slot];
      bf[0] = *(const bf16x8*)&Ws[wn * 32 +      l16][slot];
      bf[1] = *(const bf16x8*)&Ws[wn * 32 + 16 + l16][slot];
#pragma unroll
      for (int i = 0; i < 2; ++i)
#pragma unroll
        for (int j = 0; j < 2; ++j)
          acc[i][j] = __builtin_amdgcn_mfma_f32_16x16x32_bf16(af[i], bf[j], acc[i][j], 0, 0, 0);
    }
  }

#pragma unroll
  for (int i = 0; i < 2; ++i)
#pragma unroll
    for (int j = 0; j < 2; ++j) {
      const int col = bnb * 64 + wn * 32 + j * 16 + l16;
      const float bias_v = bias[col];
#pragma unroll
      for (int r = 0; r < 4; ++r) {
        const int row = bm * 64 + wm * 32 + i * 16 + quad * 4 + r;
        float v = acc[i][j][r] + bias_v;
        const size_t o = (size_t)row * Nout + col;
        if constexpr (EPI == 1) {
          ((float*)outp)[o] = v;
        } else if constexpr (EPI == 2) {
          float gl = 0.5f * v * (1.0f + erff(v * 0.70710678118654752f));
          ((u16*)outp)[o] = f2b(gl);
        } else {
          ((u16*)outp)[o] = f2b(0.5f * mloc[o] + 0.5f * v);
        }
      }
    }
}

// ---------------- 128x128 tile GEMM (glls, BK=64) + hist slice (y==16) ------
__global__ __launch_bounds__(256) void gemm128(
    const u16* __restrict__ A, const u16* __restrict__ W,
    const float* __restrict__ bias0, const float* __restrict__ bias1,
    u16* __restrict__ out0, u16* __restrict__ out1,
    int M, int Nout, int K,
    const int* __restrict__ ei, int* __restrict__ deg)
{
  const int tid  = threadIdx.x;
  if (blockIdx.y == 16) {             // fused degree histogram (32 blocks)
#pragma unroll
    for (int i = 0; i < 16; ++i) {
      const int e = blockIdx.x * 4096 + i * 256 + tid;
      atomicAdd(&deg[ei[E_EDGES + e]], 1);
    }
    return;
  }
  const int lane = tid & 63, wave = tid >> 6;
  const int quad = lane >> 4, l16 = lane & 15;
  const int wm = wave >> 1, wn = wave & 1;   // 2x2 wave grid, 64x64 per wave
  const int bm = blockIdx.x, bnb = blockIdx.y;

  __shared__ __align__(16) u16 As[128][64];
  __shared__ __align__(16) u16 Ws[128][64];

  f32x4 acc[4][4] = {};

  const int lr = lane >> 3, gs = lane & 7;
  const int g8 = (gs ^ lr) * 8;
  const u16* ab = A + (size_t)(bm  * 128 + wave * 32 + lr) * K + g8;
  const u16* wb = W + (size_t)(bnb * 128 + wave * 32 + lr) * K + g8;

  for (int k0 = 0; k0 < K; k0 += 64) {
    __syncthreads();
#pragma unroll
    for (int c = 0; c < 4; ++c) {
      glds16(ab + (size_t)(c * 8) * K + k0, &As[wave * 32 + c * 8][0]);
      glds16(wb + (size_t)(c * 8) * K + k0, &Ws[wave * 32 + c * 8][0]);
    }
    __syncthreads();
#pragma unroll
    for (int ks = 0; ks < 2; ++ks) {
      const int slot = ((ks * 4 + quad) ^ (l16 & 7)) * 8;
      bf16x8 af[4], bf[4];
#pragma unroll
      for (int am = 0; am < 4; ++am)
        af[am] = *(const bf16x8*)&As[wm * 64 + am * 16 + l16][slot];
#pragma unroll
      for (int bn = 0; bn < 4; ++bn)
        bf[bn] = *(const bf16x8*)&Ws[wn * 64 + bn * 16 + l16][slot];
#pragma unroll
      for (int am = 0; am < 4; ++am)
#pragma unroll
        for (int bn = 0; bn < 4; ++bn)
          acc[am][bn] = __builtin_amdgcn_mfma_f32_16x16x32_bf16(af[am], bf[bn], acc[am][bn], 0, 0, 0);
    }
  }

#pragma unroll
  for (int am = 0; am < 4; ++am)
#pragma unroll
    for (int bn = 0; bn < 4; ++bn) {
      const int col = bnb * 128 + wn * 64 + bn * 16 + l16;
      const float bias_v = (col < 512) ? bias0[col] : bias1[col - 512];
#pragma unroll
      for (int r = 0; r < 4; ++r) {
        const int row = bm * 128 + wm * 64 + am * 16 + quad * 4 + r;
        float v = acc[am][bn][r] + bias_v;
        if (col < 512) out0[(size_t)row * 512 + col] = f2b(v);
        else           out1[(size_t)row * 1536 + (col - 512)] = f2b(v);
      }
    }
}

// ---------------- scan (bx==512) + V transpose (bx<512), one dispatch -------
__global__ __launch_bounds__(256) void scan_vtrans(
    const int* __restrict__ deg, int* __restrict__ off, int* __restrict__ cursor,
    const u16* __restrict__ qkv, u16* __restrict__ vt)
{
  if (blockIdx.x == 512) {            // exclusive scan of 4096 degrees
    __shared__ int part[256];
    const int t = threadIdx.x;
    int v[16];
    int s = 0;
#pragma unroll
    for (int i = 0; i < 16; ++i) { v[i] = deg[t * 16 + i]; s += v[i]; }
    part[t] = s;
    __syncthreads();
    for (int d = 1; d < 256; d <<= 1) {
      int val = (t >= d) ? part[t - d] : 0;
      __syncthreads();
      if (t >= d) part[t] += val;
      __syncthreads();
    }
    int prefix = (t == 0) ? 0 : part[t - 1];
#pragma unroll
    for (int i = 0; i < 16; ++i) {
      off[t * 16 + i] = prefix;
      cursor[t * 16 + i] = prefix;
      prefix += v[i];
    }
    if (t == 255) off[4096] = prefix;
    return;
  }
  // vtrans: vt[h][d][m] = V[m][h][d]
  const int tid = threadIdx.x;
  const int d = tid & 63, mg = tid >> 6;
  const int h = blockIdx.x >> 6, mt = blockIdx.x & 63;
  const int m0 = mt * 64 + mg * 16;
  u16 buf[16];
#pragma unroll
  for (int i = 0; i < 16; ++i)
    buf[i] = qkv[(size_t)(m0 + i) * 1536 + 1024 + h * 64 + d];
  u16x8 w0, w1;
#pragma unroll
  for (int i = 0; i < 8; ++i) { w0[i] = buf[i]; w1[i] = buf[8 + i]; }
  u16* op = vt + (size_t)(h * 64 + d) * N_NODES + m0;
  *(u16x8*)op = w0;
  *(u16x8*)(op + 8) = w1;
}

// ---------------- flash attention (+ fill slice at z==SPLITS) ---------------
// VALU lsum + 16-lane shuffle (VGPR 64 loop); bf16 split partials.
template<int SPLITS>
__global__ __launch_bounds__(256) void attn_kernel(
    const u16* __restrict__ qkv, const u16* __restrict__ vt,
    u16* __restrict__ opart, float* __restrict__ lpart,
    const int* __restrict__ ei, int* __restrict__ cursor, int* __restrict__ csr)
{
  const int tid = threadIdx.x, wave = tid >> 6, lane = tid & 63;
  const int split = blockIdx.z;
  if (split == SPLITS) {              // fused CSR fill (256 blocks, 2 edges/thr)
    const int sblk = blockIdx.y * 32 + blockIdx.x;
#pragma unroll
    for (int i = 0; i < 2; ++i) {
      const int e = sblk * 512 + i * 256 + tid;
      const int s = ei[e];
      const int d = ei[E_EDGES + e];
      const int p = atomicAdd(&cursor[d], 1);
      csr[p] = s;
    }
    return;
  }
  const int quad = lane >> 4, l16 = lane & 15;
  const int h = blockIdx.y, tile = blockIdx.x;

  __shared__ __align__(16) u16 Ks[64][64];    // K tile, XOR-swizzled
  __shared__ __align__(16) u16 Vts[64][64];   // V^T tile, XOR-swizzled
  __shared__ __align__(16) u16 Ps[128][72];   // P [row][m'] (padded, VALU-written)

  const float QSCALE = 0.18033688011112042f;  // log2(e)/8
  bf16x8 aq[2][2];
#pragma unroll
  for (int mb = 0; mb < 2; ++mb) {
    const int qrow = tile * 128 + wave * 32 + mb * 16 + l16;
    const u16* qp = qkv + (size_t)qrow * 1536 + h * 64 + quad * 8;
    u16x8 q0 = *(const u16x8*)qp;
    u16x8 q1 = *(const u16x8*)(qp + 32);
    u16x8 s0, s1;
#pragma unroll
    for (int i = 0; i < 8; ++i) {
      s0[i] = f2b(b2f(q0[i]) * QSCALE);
      s1[i] = f2b(b2f(q1[i]) * QSCALE);
    }
    aq[mb][0] = __builtin_bit_cast(bf16x8, s0);
    aq[mb][1] = __builtin_bit_cast(bf16x8, s1);
  }

  f32x4 O[2][4] = {};
  float lsum[2][4] = {};   // per-lane partial row sums

  const int lr = lane >> 3, gs = lane & 7;
  const int g8 = (gs ^ lr) * 8;
  const int R0 = wave * 16 + lr;

  const int mt1 = (split + 1) * (64 / SPLITS);
  for (int mt = split * (64 / SPLITS); mt < mt1; ++mt) {
    __syncthreads();
    glds16(qkv + (size_t)(mt * 64 + R0)     * 1536 + 512 + h * 64 + g8, &Ks[wave * 16][0]);
    glds16(qkv + (size_t)(mt * 64 + R0 + 8) * 1536 + 512 + h * 64 + g8, &Ks[wave * 16 + 8][0]);
    glds16(vt + (size_t)(h * 64 + R0)     * N_NODES + mt * 64 + g8, &Vts[wave * 16][0]);
    glds16(vt + (size_t)(h * 64 + R0 + 8) * N_NODES + mt * 64 + g8, &Vts[wave * 16 + 8][0]);
    __syncthreads();

    // S = (cQ) K^T
    f32x4 s[2][4] = {};
#pragma unroll
    for (int ks = 0; ks < 2; ++ks) {
      const int slot = ((ks * 4 + quad) ^ (l16 & 7)) * 8;
      bf16x8 bk[4];
#pragma unroll
      for (int jn = 0; jn < 4; ++jn)
        bk[jn] = *(const bf16x8*)&Ks[jn * 16 + l16][slot];
#pragma unroll
      for (int mb = 0; mb < 2; ++mb)
#pragma unroll
        for (int jn = 0; jn < 4; ++jn)
          s[mb][jn] = __builtin_amdgcn_mfma_f32_16x16x32_bf16(aq[mb][ks], bk[jn], s[mb][jn], 0, 0, 0);
    }

    // p = exp2(s); accumulate per-lane partial sums; half-up bf16 store
#pragma unroll
    for (int mb = 0; mb < 2; ++mb)
#pragma unroll
      for (int jn = 0; jn < 4; ++jn)
#pragma unroll
        for (int r = 0; r < 4; ++r) {
          float p = __builtin_amdgcn_exp2f(s[mb][jn][r]);
          lsum[mb][r] += p;
          Ps[wave * 32 + mb * 16 + quad * 4 + r][jn * 16 + l16] = f2b_up(p);
        }
    // no barrier: Ps rows are wave-private; lgkmcnt ordering handles RAW

    // O += P V
#pragma unroll
    for (int ks = 0; ks < 2; ++ks) {
      const int slot = ((ks * 4 + quad) ^ (l16 & 7)) * 8;
      bf16x8 bv[4];
#pragma unroll
      for (int jd = 0; jd < 4; ++jd)
        bv[jd] = *(const bf16x8*)&Vts[jd * 16 + l16][slot];
#pragma unroll
      for (int mb = 0; mb < 2; ++mb) {
        bf16x8 ap = *(const bf16x8*)&Ps[wave * 32 + mb * 16 + l16][ks * 32 + quad * 8];
#pragma unroll
        for (int jd = 0; jd < 4; ++jd)
          O[mb][jd] = __builtin_amdgcn_mfma_f32_16x16x32_bf16(ap, bv[jd], O[mb][jd], 0, 0, 0);
      }
    }
  }

  // one-time 16-lane reduce of row-sum partials
#pragma unroll
  for (int mb = 0; mb < 2; ++mb)
#pragma unroll
    for (int r = 0; r < 4; ++r)
#pragma unroll
      for (int off = 1; off < 16; off <<= 1)
        lsum[mb][r] += __shfl_xor(lsum[mb][r], off);

  // write unnormalized partials (bf16) + row sums
#pragma unroll
  for (int mb = 0; mb < 2; ++mb)
#pragma unroll
    for (int r = 0; r < 4; ++r) {
      const int row = tile * 128 + wave * 32 + mb * 16 + quad * 4 + r;
      u16* orow = opart + ((size_t)split * N_NODES + row) * C_DIM + h * 64;
#pragma unroll
      for (int jd = 0; jd < 4; ++jd)
        orow[jd * 16 + l16] = f2b(O[mb][jd][r]);
      if (l16 == 0)
        lpart[((size_t)split * N_NODES + row) * H_HEADS + h] = lsum[mb][r];
    }
}

// ---------------- combine (y==1) + gather-mean (y==0), one dispatch ---------
template<int SPLITS>
__global__ __launch_bounds__(256) void combine_gather(
    const u16* __restrict__ opart, const float* __restrict__ lpart,
    u16* __restrict__ ctx,
    const int* __restrict__ off, const int* __restrict__ csr,
    const u16* __restrict__ lh, float* __restrict__ lo)
{
  if (blockIdx.y == 0) {              // gather: one wave per dst node
    const int wave = threadIdx.x >> 6, lane = threadIdx.x & 63;
    const int n = blockIdx.x * 4 + wave;
    const int j0 = off[n], j1 = off[n + 1];
    float acc[8] = {};
    for (int j = j0; j < j1; ++j) {
      const int s = csr[j];
      const u16x8 v = *(const u16x8*)(lh + (size_t)s * C_DIM + lane * 8);
#pragma unroll
      for (int i = 0; i < 8; ++i) acc[i] += b2f(v[i]);
    }
    const float inv = 1.0f / fmaxf((float)(j1 - j0), 1.0f);
    f32x4 o0, o1;
#pragma unroll
    for (int i = 0; i < 4; ++i) { o0[i] = acc[i] * inv; o1[i] = acc[4 + i] * inv; }
    float* op = lo + (size_t)n * C_DIM + lane * 8;
    *(f32x4*)op = o0;
    *(f32x4*)(op + 4) = o1;
    return;
  }
  // combine split partials
  const size_t base = (size_t)(blockIdx.x * 256 + threadIdx.x) * 8;
  const int row = (int)(base >> 9);
  const int h = (int)((base & 511) >> 6);
  float l = 0.0f;
#pragma unroll
  for (int s = 0; s < SPLITS; ++s)
    l += lpart[(size_t)s * N_NODES * H_HEADS + (size_t)row * H_HEADS + h];
  const float inv = 1.0f / l;
  float o[8] = {};
#pragma unroll
  for (int s = 0; s < SPLITS; ++s) {
    const u16x8 p = *(const u16x8*)(opart + (size_t)s * N_NODES * C_DIM + base);
#pragma unroll
    for (int i = 0; i < 8; ++i) o[i] += b2f(p[i]);
  }
  u16x8 ob;
#pragma unroll
  for (int i = 0; i < 8; ++i) ob[i] = f2b(o[i] * inv);
  *(u16x8*)(ctx + base) = ob;
}

// ---------------- LayerNorms (one wave per row) ----------------
__global__ __launch_bounds__(256) void ln1_kernel(
    const float* __restrict__ x, const float* __restrict__ pr,
    const float* __restrict__ g, const float* __restrict__ b,
    u16* __restrict__ hb, float* __restrict__ hf)
{
  const int wave = threadIdx.x >> 6, lane = threadIdx.x & 63;
  const int row = blockIdx.x * 4 + wave;
  const int c0 = lane * 8;
  const size_t base = (size_t)row * C_DIM + c0;
  f32x4 x0 = *(const f32x4*)(x + base);
  f32x4 x1 = *(const f32x4*)(x + base + 4);
  f32x4 p0 = *(const f32x4*)(pr + base);
  f32x4 p1 = *(const f32x4*)(pr + base + 4);
  float v[8];
#pragma unroll
  for (int i = 0; i < 4; ++i) { v[i] = x0[i] + p0[i]; v[4 + i] = x1[i] + p1[i]; }
  float sum = 0, sq = 0;
#pragma unroll
  for (int i = 0; i < 8; ++i) { sum += v[i]; sq += v[i] * v[i]; }
  for (int off = 1; off < 64; off <<= 1) { sum += __shfl_xor(sum, off); sq += __shfl_xor(sq, off); }
  const float mean = sum * (1.0f / C_DIM);
  const float var  = sq * (1.0f / C_DIM) - mean * mean;
  const float rstd = rsqrtf(var + 1e-5f);
  f32x4 g0 = *(const f32x4*)(g + c0), g1 = *(const f32x4*)(g + c0 + 4);
  f32x4 b0 = *(const f32x4*)(b + c0), b1 = *(const f32x4*)(b + c0 + 4);
  u16x8 ob; f32x4 h0, h1;
#pragma unroll
  for (int i = 0; i < 4; ++i) {
    float hv0 = (v[i]     - mean) * rstd * g0[i] + b0[i];
    float hv1 = (v[4 + i] - mean) * rstd * g1[i] + b1[i];
    h0[i] = hv0; h1[i] = hv1;
    ob[i] = f2b(hv0); ob[4 + i] = f2b(hv1);
  }
  *(u16x8*)(hb + base) = ob;
  *(f32x4*)(hf + base) = h0;
  *(f32x4*)(hf + base + 4) = h1;
}

__global__ __launch_bounds__(256) void ln2_kernel(
    const float* __restrict__ a, const float* __restrict__ c,
    const float* __restrict__ g, const float* __restrict__ b,
    float* __restrict__ out)
{
  const int wave = threadIdx.x >> 6, lane = threadIdx.x & 63;
  const int row = blockIdx.x * 4 + wave;
  const int c0 = lane * 8;
  const size_t base = (size_t)row * C_DIM + c0;
  f32x4 a0 = *(const f32x4*)(a + base), a1 = *(const f32x4*)(a + base + 4);
  f32x4 c0v = *(const f32x4*)(c + base), c1v = *(const f32x4*)(c + base + 4);
  float v[8];
#pragma unroll
  for (int i = 0; i < 4; ++i) { v[i] = a0[i] + c0v[i]; v[4 + i] = a1[i] + c1v[i]; }
  float sum = 0, sq = 0;
#pragma unroll
  for (int i = 0; i < 8; ++i) { sum += v[i]; sq += v[i] * v[i]; }
  for (int off = 1; off < 64; off <<= 1) { sum += __shfl_xor(sum, off); sq += __shfl_xor(sq, off); }
  const float mean = sum * (1.0f / C_DIM);
  const float var  = sq * (1.0f / C_DIM) - mean * mean;
  const float rstd = rsqrtf(var + 1e-5f);
  f32x4 g0 = *(const f32x4*)(g + c0), g1 = *(const f32x4*)(g + c0 + 4);
  f32x4 b0 = *(const f32x4*)(b + c0), b1 = *(const f32x4*)(b + c0 + 4);
  f32x4 h0, h1;
#pragma unroll
  for (int i = 0; i < 4; ++i) {
    h0[i] = (v[i]     - mean) * rstd * g0[i] + b0[i];
    h1[i] = (v[4 + i] - mean) * rstd * g1[i] + b1[i];
  }
  *(f32x4*)(out + base) = h0;
  *(f32x4*)(out + base + 4) = h1;
}

// ---------------- launch ----------------
extern "C" void kernel_launch(void* const* d_in, const int* in_sizes, int n_in,
                              void* d_out, int out_size, void* d_ws, size_t ws_size,
                              hipStream_t stream) {
  const float* x          = (const float*)d_in[0];
  const int*   ei         = (const int*)d_in[1];
  const float* local_w    = (const float*)d_in[2];
  const float* local_b    = (const float*)d_in[3];
  const float* in_proj_w  = (const float*)d_in[4];
  const float* in_proj_b  = (const float*)d_in[5];
  const float* attn_out_w = (const float*)d_in[6];
  const float* attn_out_b = (const float*)d_in[7];
  const float* output_w   = (const float*)d_in[8];
  const float* output_b   = (const float*)d_in[9];
  const float* n1g = (const float*)d_in[10];
  const float* n1b = (const float*)d_in[11];
  const float* n2g = (const float*)d_in[12];
  const float* n2b = (const float*)d_in[13];
  const float* ffn_w1 = (const float*)d_in[14];
  const float* ffn_b1 = (const float*)d_in[15];
  const float* ffn_w2 = (const float*)d_in[16];
  const float* ffn_b2 = (const float*)d_in[17];
  float* out = (float*)d_out;

  char* ws = (char*)d_ws;
  size_t o = 0;
  float* local_out = (float*)(ws + o); o += (size_t)N_NODES * C_DIM * 4;  // 8 MB
  int* deg    = (int*)(ws + o); o += (N_NODES) * 4;
  int* off    = (int*)(ws + o); o += (N_NODES + 16) * 4;
  int* cursor = (int*)(ws + o); o += (N_NODES) * 4;
  int* csr    = (int*)(ws + o); o += (size_t)E_EDGES * 4;
  u16* xb   = (u16*)(ws + o); o += (size_t)N_NODES * C_DIM * 2;           // 4 MB
  u16* wbLQ = (u16*)(ws + o); o += (size_t)4 * C_DIM * C_DIM * 2;         // 2 MB
  u16* wbA  = (u16*)(ws + o); o += (size_t)C_DIM * C_DIM * 2;
  u16* wbO  = (u16*)(ws + o); o += (size_t)C_DIM * C_DIM * 2;
  u16* wbF1 = (u16*)(ws + o); o += (size_t)2 * C_DIM * C_DIM * 2;
  u16* wbF2 = (u16*)(ws + o); o += (size_t)2 * C_DIM * C_DIM * 2;
  u16* local_h   = (u16*)(ws + o); o += (size_t)N_NODES * C_DIM * 2;
  u16* qkvb      = (u16*)(ws + o); o += (size_t)N_NODES * 3 * C_DIM * 2;  // 12 MB
  u16* ctxb      = (u16*)(ws + o); o += (size_t)N_NODES * C_DIM * 2;
  u16* mixed     = (u16*)(ws + o); o += (size_t)N_NODES * C_DIM * 2;
  u16* hidden_bf = (u16*)(ws + o); o += (size_t)N_NODES * C_DIM * 2;      // 4 MB
  float* hidden_f = (float*)(ws + o); o += (size_t)N_NODES * C_DIM * 4;   // 8 MB
  u16* ff1       = (u16*)(ws + o); o += (size_t)N_NODES * 2 * C_DIM * 2;  // 8 MB
  // aliases (dead ranges reused):
  float* proj  = (float*)qkvb;       // qkv dead after attn; proj 8 MB <= 12 MB
  float* ff2   = (float*)local_out;  // local_out dead after mix-epilogue gemm
  u16*   vt    = xb;                 // xb dead after LQKV gemm; 4 MB
  // SPLITS=4 bf16 partials (16.25 MB) past static region if workspace allows
  u16* opart4 = (u16*)(ws + o);
  float* lpart4 = (float*)(ws + o + (size_t)4 * N_NODES * C_DIM * 2);
  const size_t need4 = o + (size_t)4 * N_NODES * C_DIM * 2 + (size_t)4 * N_NODES * H_HEADS * 4;
  const bool use4 = (ws_size >= need4);
  // SPLITS=2 fallback: inside hidden_bf..ff1 region (8.25 MB <= 20 MB)
  u16* opart2 = (u16*)hidden_bf;
  float* lpart2 = (float*)(opart2 + (size_t)2 * N_NODES * C_DIM);

  // D1: fp32 -> bf16 conversions + deg zeroing (slice t==7)
  CvtArgs ca;
  ca.src[0] = x;          ca.dst[0] = xb;   ca.n[0] = N_NODES * C_DIM;
  ca.src[1] = local_w;    ca.dst[1] = wbLQ;                  ca.n[1] = C_DIM * C_DIM;
  ca.src[2] = in_proj_w;  ca.dst[2] = wbLQ + C_DIM * C_DIM;  ca.n[2] = 3 * C_DIM * C_DIM;
  ca.src[3] = attn_out_w; ca.dst[3] = wbA;  ca.n[3] = C_DIM * C_DIM;
  ca.src[4] = output_w;   ca.dst[4] = wbO;  ca.n[4] = C_DIM * C_DIM;
  ca.src[5] = ffn_w1;     ca.dst[5] = wbF1; ca.n[5] = 2 * C_DIM * C_DIM;
  ca.src[6] = ffn_w2;     ca.dst[6] = wbF2; ca.n[6] = 2 * C_DIM * C_DIM;
  ca.deg = deg;
  cvt_multi<<<dim3(N_NODES * C_DIM / 2048, 8), 256, 0, stream>>>(ca);

  // D2: merged local+qkv GEMM + degree histogram (y==16)
  gemm128<<<dim3(32, 17), 256, 0, stream>>>(xb, wbLQ, local_b, in_proj_b,
      local_h, qkvb, N_NODES, 4 * C_DIM, C_DIM, ei, deg);

  // D3: scan (bx==512) + V transpose (bx<512); xb dead after D2
  scan_vtrans<<<513, 256, 0, stream>>>(deg, off, cursor, qkvb, vt);

  // D4: attention + CSR fill (z==SPLITS); D5: combine + gather
  if (use4) {
    attn_kernel<4><<<dim3(32, 8, 5), 256, 0, stream>>>(qkvb, vt, opart4, lpart4,
        ei, cursor, csr);
    combine_gather<4><<<dim3(1024, 2), 256, 0, stream>>>(opart4, lpart4, ctxb,
        off, csr, local_h, local_out);
  } else {
    attn_kernel<2><<<dim3(32, 8, 3), 256, 0, stream>>>(qkvb, vt, opart2, lpart2,
        ei, cursor, csr);
    combine_gather<2><<<dim3(1024, 2), 256, 0, stream>>>(opart2, lpart2, ctxb,
        off, csr, local_h, local_out);
  }

  // D6: mixed = 0.5*local_out + 0.5*(ctx @ attn_out_w^T + b)
  gemm_bt<3><<<dim3(64, 8), 256, 0, stream>>>(ctxb, wbA, attn_out_b, mixed,
      N_NODES, C_DIM, C_DIM, local_out);

  // D7: proj = mixed @ output_w^T + b ; D8: hidden = LN(x + proj)
  gemm_bt<1><<<dim3(64, 8), 256, 0, stream>>>(mixed, wbO, output_b, proj,
      N_NODES, C_DIM, C_DIM, nullptr);
  ln1_kernel<<<N_NODES / 4, 256, 0, stream>>>(x, proj, n1g, n1b, hidden_bf, hidden_f);

  // D9-D11: FFN + LN2
  gemm_bt<2><<<dim3(64, 16), 256, 0, stream>>>(hidden_bf, wbF1, ffn_b1, ff1,
      N_NODES, 2 * C_DIM, C_DIM, nullptr);
  gemm_bt<1><<<dim3(64, 8), 256, 0, stream>>>(ff1, wbF2, ffn_b2, ff2,
      N_NODES, C_DIM, 2 * C_DIM, nullptr);
  ln2_kernel<<<N_NODES / 4, 256, 0, stream>>>(hidden_f, ff2, n2g, n2b, out);
}